// Round 11
// baseline (403.017 us; speedup 1.0000x reference)
//
#include <hip/hip_runtime.h>
#include <cmath>

#define RMAXF 5.0f
#define INV_AVG (1.0f/16.0f)
#define SQ4PI 3.5449077018110318f
#define NPTS 4096
#define TAB_SCALE ((float)(NPTS-1)/RMAXF)

typedef _Float16 h2 __attribute__((ext_vector_type(2)));

__device__ __forceinline__ h2 as_h2(unsigned int u){ h2 r; __builtin_memcpy(&r,&u,4); return r; }
__device__ __forceinline__ unsigned int as_u32(h2 h){ unsigned int u; __builtin_memcpy(&u,&h,4); return u; }
__device__ __forceinline__ unsigned int pk16(float a, float b){
  h2 t; t[0] = (_Float16)a; t[1] = (_Float16)b; return as_u32(t);
}
__device__ __forceinline__ float fdot2(h2 a, h2 b, float c){ return __builtin_amdgcn_fdot2(a,b,c,false); }

// Real sph harmonics l=0..3 (times sqrt(4pi)) of unit vector (x,y,z)
__device__ __forceinline__ void sph16(float x, float y, float z, float* Y){
  float x2=x*x, y2=y*y, z2=z*z;
  Y[0]=SQ4PI*0.28209479177387814f;
  Y[1]=SQ4PI*0.4886025119029199f*y;
  Y[2]=SQ4PI*0.4886025119029199f*z;
  Y[3]=SQ4PI*0.4886025119029199f*x;
  Y[4]=SQ4PI*1.0925484305920792f*x*y;
  Y[5]=SQ4PI*1.0925484305920792f*y*z;
  Y[6]=SQ4PI*0.31539156525252005f*(3.f*z2-1.f);
  Y[7]=SQ4PI*1.0925484305920792f*x*z;
  Y[8]=SQ4PI*0.5462742152960396f*(x2-y2);
  Y[9]=SQ4PI*0.5900435899266435f*y*(3.f*x2-y2);
  Y[10]=SQ4PI*2.890611442640554f*x*y*z;
  Y[11]=SQ4PI*0.4570457994644658f*y*(5.f*z2-1.f);
  Y[12]=SQ4PI*0.3731763325901154f*z*(5.f*z2-3.f);
  Y[13]=SQ4PI*0.4570457994644658f*x*(5.f*z2-1.f);
  Y[14]=SQ4PI*1.445305721320277f*z*(x2-y2);
  Y[15]=SQ4PI*0.5900435899266435f*x*(x2-3.f*y2);
}

// radial basis ef[8] = bess*fcut and d(ef)/dr (table builder only)
__device__ __forceinline__ void radial(float r, float* ef, float* def){
  const float PI_ = 3.14159265358979323846f;
  const float c = 0.6324555320336759f; // sqrt(2/5)
  float xr = r*(1.0f/RMAXF);
  float x2=xr*xr, x3=x2*xr, x5=x3*x2, x6=x5*xr, x7=x6*xr, x8=x7*xr;
  float fcut = 1.f - 28.f*x6 + 48.f*x7 - 21.f*x8;
  float om = 1.f - xr;
  float dfcut = -168.f*x5*om*om*(1.0f/RMAXF);
  float invr = 1.f/r;
  #pragma unroll
  for(int n=1;n<=8;n++){
    float a = (float)n*PI_*(1.0f/RMAXF);
    float ar = a*r;
    float s, co;
    sincosf(ar, &s, &co);
    float b = c*s*invr;
    ef[n-1] = b*fcut;
    def[n-1] = c*(a*co - s*invr)*invr*fcut + b*dfcut;
  }
}

// ---------------- build radial tables: w(r), dw/dr(r), 64 channels --------
__global__ __launch_bounds__(64) void tab_k(
    const float* __restrict__ W_r1, const float* __restrict__ W_r2,
    float* __restrict__ w_tab, float* __restrict__ dw_tab)
{
  __shared__ float s_sil[64], s_ds[64];
  int p = blockIdx.x, lane = threadIdx.x;
  float r = fmaxf((float)p * (RMAXF/(float)(NPTS-1)), 1e-6f);
  float ef[8], def[8];
  radial(r, ef, def);
  float t = 0.f, dt = 0.f;
  #pragma unroll
  for(int j=0;j<8;j++){ t += ef[j]*W_r1[j*64+lane]; dt += def[j]*W_r1[j*64+lane]; }
  float sig = 1.f/(1.f+expf(-t));
  s_sil[lane] = t*sig;
  s_ds[lane]  = sig*(1.f + t*(1.f-sig))*dt;
  __syncthreads();
  float w = 0.f, dw = 0.f;
  for(int j=0;j<64;j++){
    w  += s_sil[j]*W_r2[j*64+lane];
    dw += s_ds[j] *W_r2[j*64+lane];
  }
  w_tab[p*64+lane]  = w;
  dw_tab[p*64+lane] = dw;
}

// ---------------- node embed: h = attrs @ W_embed, e0 atomic per graph ----
__global__ __launch_bounds__(64) void embed_k(
    const float* __restrict__ attrs, const float* __restrict__ W_embed,
    const float* __restrict__ ae, const int* __restrict__ batch,
    float* __restrict__ h, float* __restrict__ e_acc, int N)
{
  int n = blockIdx.x;
  if(n >= N) return;
  int k = threadIdx.x;
  float acc = 0.f;
  #pragma unroll
  for(int s=0;s<10;s++) acc += attrs[n*10+s]*W_embed[s*64+k];
  h[(size_t)n*64+k] = acc;
  if(k==0){
    float e0 = 0.f;
    #pragma unroll
    for(int s=0;s<10;s++) e0 += attrs[n*10+s]*ae[s];
    atomicAdd(&e_acc[batch[n]*2+0], e0);
  }
}

// ---------------- pack W_mix as f16 pairs, both orientations --------------
// Wpc[l][c][kp] = half2(W[l][2kp][c], W[l][2kp+1][c])   (fwd: lane=c column)
// Wpr[l][k][cp] = half2(W[l][k][2cp], W[l][k][2cp+1])   (bwd: lane=k row)
__global__ void pack_k(const float* __restrict__ W_mix,
                       unsigned int* __restrict__ Wpc,
                       unsigned int* __restrict__ Wpr){
  int i = threadIdx.x + blockIdx.x*blockDim.x;
  if(i < 8192){
    int l = i >> 11, a = (i >> 5) & 63, p = i & 31;
    Wpc[i] = pk16(W_mix[l*4096 + (2*p)*64 + a], W_mix[l*4096 + (2*p+1)*64 + a]);
    Wpr[i] = pk16(W_mix[l*4096 + a*64 + 2*p], W_mix[l*4096 + a*64 + 2*p+1]);
  }
}

// ---------------- CSR build over surviving edges (r < RMAX), key = recv ---
__global__ __launch_bounds__(256) void count_k(
    const float* __restrict__ pos, const float* __restrict__ shifts,
    const int* __restrict__ eidx, int* __restrict__ deg, int E)
{
  int e = blockIdx.x*256 + threadIdx.x;
  if(e >= E) return;
  int snd = eidx[e], rcv = eidx[E+e];
  float vx = pos[rcv*3+0]-pos[snd*3+0]+shifts[e*3+0];
  float vy = pos[rcv*3+1]-pos[snd*3+1]+shifts[e*3+1];
  float vz = pos[rcv*3+2]-pos[snd*3+2]+shifts[e*3+2];
  float r2 = vx*vx+vy*vy+vz*vz + 1e-12f;
  if(r2 < RMAXF*RMAXF) atomicAdd(&deg[rcv], 1);
}

__global__ __launch_bounds__(256) void scan_k(
    const int* __restrict__ deg, int* __restrict__ rowptr,
    int* __restrict__ cursor, int N)
{
  __shared__ int part[256];
  int tid = threadIdx.x;
  int chunk = (N + 255) / 256;
  int begin = tid*chunk, end = begin+chunk < N ? begin+chunk : N;
  int s = 0;
  for(int i=begin;i<end;i++) s += deg[i];
  part[tid] = s;
  __syncthreads();
  for(int off=1; off<256; off<<=1){
    int t = (tid >= off) ? part[tid-off] : 0;
    __syncthreads();
    part[tid] += t;
    __syncthreads();
  }
  int run = part[tid] - s;   // exclusive prefix of this thread's chunk
  for(int i=begin;i<end;i++){
    rowptr[i] = run; cursor[i] = run; run += deg[i];
  }
  if(tid == 255) rowptr[N] = part[255];
}

__global__ __launch_bounds__(256) void scatter_k(
    const float* __restrict__ pos, const float* __restrict__ shifts,
    const int* __restrict__ eidx, int* __restrict__ cursor,
    int* __restrict__ elist, int E)
{
  int e = blockIdx.x*256 + threadIdx.x;
  if(e >= E) return;
  int snd = eidx[e], rcv = eidx[E+e];
  float vx = pos[rcv*3+0]-pos[snd*3+0]+shifts[e*3+0];
  float vy = pos[rcv*3+1]-pos[snd*3+1]+shifts[e*3+1];
  float vz = pos[rcv*3+2]-pos[snd*3+2]+shifts[e*3+2];
  float r2 = vx*vx+vy*vy+vz*vz + 1e-12f;
  if(r2 < RMAXF*RMAXF){
    int p = atomicAdd(&cursor[rcv], 1);
    elist[p] = e;
  }
}

// ---------------- edge forward: one wave per node; A stored as f16 pairs --
__global__ __launch_bounds__(256) void fwd_tab(
    const float* __restrict__ pos, const float* __restrict__ shifts,
    const int* __restrict__ eidx, const float* __restrict__ h,
    const float* __restrict__ w_tab,
    const int* __restrict__ rowptr, const int* __restrict__ elist,
    unsigned int* __restrict__ Ah, int N, int E)
{
  int tid = threadIdx.x, ws4 = tid >> 6, lane = tid & 63;
  int n = blockIdx.x*4 + ws4;
  if(n >= N) return;
  int beg = rowptr[n], endp = rowptr[n+1];
  float acc[16];
  #pragma unroll
  for(int lm=0;lm<16;lm++) acc[lm] = 0.f;
  float px = pos[n*3+0], py = pos[n*3+1], pz = pos[n*3+2];
  for(int idx=beg; idx<endp; idx++){
    int e = elist[idx];
    int snd = eidx[e];
    float vx = px - pos[snd*3+0] + shifts[e*3+0];
    float vy = py - pos[snd*3+1] + shifts[e*3+1];
    float vz = pz - pos[snd*3+2] + shifts[e*3+2];
    float r = sqrtf(vx*vx+vy*vy+vz*vz + 1e-12f);
    float invr = 1.f/r;
    float Y[16]; sph16(vx*invr, vy*invr, vz*invr, Y);
    float rs = r*TAB_SCALE;
    int i0 = (int)rs; i0 = i0 < NPTS-2 ? i0 : NPTS-2;
    float fr = rs - (float)i0;
    const float* t0 = w_tab + i0*64 + lane;
    float w0 = t0[0], w1 = t0[64];
    float w = w0 + fr*(w1-w0);
    float wh = w * h[(size_t)snd*64+lane] * INV_AVG;
    #pragma unroll
    for(int lm=0;lm<16;lm++) acc[lm] += wh*Y[lm];
  }
  // pack lane-pairs (k even/odd) to f16x2 and store
  unsigned int* Ab = Ah + (size_t)n*512 + (lane>>1);
  #pragma unroll
  for(int lm=0;lm<16;lm++){
    float nb = __shfl_xor(acc[lm], 1, 64);
    if(!(lane&1)) Ab[lm*32] = pk16(acc[lm], nb);
  }
}

// ---------------- node forward: one wave per node, all 16 lm, zero LDS ----
// All 4 W matrices in 128 packed-f16 VGPRs; A rows via wave-uniform (scalar)
// loads -> 16 independent streams; s/a0/gAm fully lane-local.
__global__ __launch_bounds__(256) void node_fwd(
    const unsigned int* __restrict__ Ah,   // [N][16][32] f16 pairs
    const unsigned int* __restrict__ Wpc,  // [4][64][32]
    const float* __restrict__ W_prod, const float* __restrict__ w_ro,
    const int* __restrict__ batch, float* __restrict__ e_acc,
    unsigned int* __restrict__ gAm, int N) // [N][16][32] f16 pairs
{
  int tid = threadIdx.x, wv = tid >> 6, lane = tid & 63;
  h2 W0[32], W1[32], W2[32], W3[32];
  {
    const uint4* q0 = (const uint4*)(Wpc + 0*2048 + lane*32);
    const uint4* q1 = (const uint4*)(Wpc + 1*2048 + lane*32);
    const uint4* q2 = (const uint4*)(Wpc + 2*2048 + lane*32);
    const uint4* q3 = (const uint4*)(Wpc + 3*2048 + lane*32);
    #pragma unroll
    for(int b=0;b<8;b++){
      uint4 r0=q0[b], r1=q1[b], r2=q2[b], r3=q3[b];
      W0[b*4+0]=as_h2(r0.x); W0[b*4+1]=as_h2(r0.y); W0[b*4+2]=as_h2(r0.z); W0[b*4+3]=as_h2(r0.w);
      W1[b*4+0]=as_h2(r1.x); W1[b*4+1]=as_h2(r1.y); W1[b*4+2]=as_h2(r1.z); W1[b*4+3]=as_h2(r1.w);
      W2[b*4+0]=as_h2(r2.x); W2[b*4+1]=as_h2(r2.y); W2[b*4+2]=as_h2(r2.z); W2[b*4+3]=as_h2(r2.w);
      W3[b*4+0]=as_h2(r3.x); W3[b*4+1]=as_h2(r3.y); W3[b*4+2]=as_h2(r3.z); W3[b*4+3]=as_h2(r3.w);
    }
  }
  float wp0 = W_prod[lane], wp1 = W_prod[64+lane], wp2 = W_prod[128+lane];
  float wr = w_ro[lane];

  for(int n = blockIdx.x*4 + wv; n < N; n += gridDim.x*4){
    unsigned int nbase = (unsigned int)__builtin_amdgcn_readfirstlane(n*512);
    const uint4* rowp = (const uint4*)(Ah + nbase);
    float am[16];
    #define FWD_ROW(WARR, LM) { \
      float acc = 0.f; \
      _Pragma("unroll") \
      for(int b=0;b<8;b++){ \
        uint4 r = rowp[(LM)*8 + b]; \
        acc = fdot2(WARR[b*4+0], as_h2(r.x), acc); \
        acc = fdot2(WARR[b*4+1], as_h2(r.y), acc); \
        acc = fdot2(WARR[b*4+2], as_h2(r.z), acc); \
        acc = fdot2(WARR[b*4+3], as_h2(r.w), acc); \
      } \
      am[LM] = acc; }
    FWD_ROW(W0,0)
    FWD_ROW(W1,1)  FWD_ROW(W1,2)  FWD_ROW(W1,3)
    FWD_ROW(W2,4)  FWD_ROW(W2,5)  FWD_ROW(W2,6)  FWD_ROW(W2,7)  FWD_ROW(W2,8)
    FWD_ROW(W3,9)  FWD_ROW(W3,10) FWD_ROW(W3,11) FWD_ROW(W3,12)
    FWD_ROW(W3,13) FWD_ROW(W3,14) FWD_ROW(W3,15)
    #undef FWD_ROW

    float s_ = 0.f;
    #pragma unroll
    for(int lm=0;lm<16;lm++) s_ += am[lm]*am[lm];
    float a0_ = am[0];
    {
      float Bv = wp0*a0_ + wp1*s_ + wp2*a0_*s_;
      float v = Bv*wr;
      #pragma unroll
      for(int off=32; off; off>>=1) v += __shfl_xor(v, off, 64);
      if(lane==0) atomicAdd(&e_acc[batch[n]*2+1], v);
    }
    float gs = wr*(wp1 + wp2*a0_);
    #pragma unroll
    for(int lm=0;lm<16;lm++){
      float g = gs*2.f*am[lm];
      if(lm==0) g += wr*(wp0 + wp2*s_);
      float nb = __shfl_xor(g, 1, 64);
      if(!(lane&1)) gAm[nbase + lm*32 + (lane>>1)] = pk16(g, nb);
    }
  }
}

// ---------------- node backward: one wave per node, all 16 lm, zero LDS ---
__global__ __launch_bounds__(256) void node_bwd(
    const unsigned int* __restrict__ gAm,  // [N][16][32] f16 pairs
    const unsigned int* __restrict__ Wpr,  // [4][64][32]
    float* __restrict__ gA, int N)         // [N][16][64] f32
{
  int tid = threadIdx.x, wv = tid >> 6, lane = tid & 63;
  h2 W0[32], W1[32], W2[32], W3[32];
  {
    const uint4* q0 = (const uint4*)(Wpr + 0*2048 + lane*32);
    const uint4* q1 = (const uint4*)(Wpr + 1*2048 + lane*32);
    const uint4* q2 = (const uint4*)(Wpr + 2*2048 + lane*32);
    const uint4* q3 = (const uint4*)(Wpr + 3*2048 + lane*32);
    #pragma unroll
    for(int b=0;b<8;b++){
      uint4 r0=q0[b], r1=q1[b], r2=q2[b], r3=q3[b];
      W0[b*4+0]=as_h2(r0.x); W0[b*4+1]=as_h2(r0.y); W0[b*4+2]=as_h2(r0.z); W0[b*4+3]=as_h2(r0.w);
      W1[b*4+0]=as_h2(r1.x); W1[b*4+1]=as_h2(r1.y); W1[b*4+2]=as_h2(r1.z); W1[b*4+3]=as_h2(r1.w);
      W2[b*4+0]=as_h2(r2.x); W2[b*4+1]=as_h2(r2.y); W2[b*4+2]=as_h2(r2.z); W2[b*4+3]=as_h2(r2.w);
      W3[b*4+0]=as_h2(r3.x); W3[b*4+1]=as_h2(r3.y); W3[b*4+2]=as_h2(r3.z); W3[b*4+3]=as_h2(r3.w);
    }
  }
  for(int n = blockIdx.x*4 + wv; n < N; n += gridDim.x*4){
    unsigned int nbase = (unsigned int)__builtin_amdgcn_readfirstlane(n*512);
    const uint4* rowp = (const uint4*)(gAm + nbase);
    float* dst = gA + (size_t)n*1024 + lane;
    #define BWD_ROW(WARR, LM) { \
      float acc = 0.f; \
      _Pragma("unroll") \
      for(int b=0;b<8;b++){ \
        uint4 r = rowp[(LM)*8 + b]; \
        acc = fdot2(WARR[b*4+0], as_h2(r.x), acc); \
        acc = fdot2(WARR[b*4+1], as_h2(r.y), acc); \
        acc = fdot2(WARR[b*4+2], as_h2(r.z), acc); \
        acc = fdot2(WARR[b*4+3], as_h2(r.w), acc); \
      } \
      dst[(LM)*64] = acc; }
    BWD_ROW(W0,0)
    BWD_ROW(W1,1)  BWD_ROW(W1,2)  BWD_ROW(W1,3)
    BWD_ROW(W2,4)  BWD_ROW(W2,5)  BWD_ROW(W2,6)  BWD_ROW(W2,7)  BWD_ROW(W2,8)
    BWD_ROW(W3,9)  BWD_ROW(W3,10) BWD_ROW(W3,11) BWD_ROW(W3,12)
    BWD_ROW(W3,13) BWD_ROW(W3,14) BWD_ROW(W3,15)
    #undef BWD_ROW
  }
}

// ---------------- edge backward: one wave per node, table lookup ----------
__global__ __launch_bounds__(256) void bwd_tab(
    const float* __restrict__ pos, const float* __restrict__ shifts,
    const int* __restrict__ eidx, const float* __restrict__ h,
    const float* __restrict__ w_tab, const float* __restrict__ dw_tab,
    const float* __restrict__ gA,
    const int* __restrict__ rowptr, const int* __restrict__ elist,
    float* __restrict__ forces, int N, int E)
{
  int tid = threadIdx.x, ws4 = tid >> 6, lane = tid & 63;
  int n = blockIdx.x*4 + ws4;
  if(n >= N) return;
  int beg = rowptr[n], endp = rowptr[n+1];
  if(beg == endp) return;
  float gm[16];
  {
    const float* gb = gA + (size_t)n*1024 + lane;
    #pragma unroll
    for(int lm=0;lm<16;lm++) gm[lm] = gb[lm*64]*INV_AVG;
  }
  float px = pos[n*3+0], py = pos[n*3+1], pz = pos[n*3+2];
  float fx=0.f, fy=0.f, fz=0.f;
  const float c1=0.4886025119029199f, c2=1.0925484305920792f, c3=0.31539156525252005f;
  const float c4=0.5462742152960396f, c5=0.5900435899266435f, c6=2.890611442640554f;
  const float c7=0.4570457994644658f, c8=0.3731763325901154f, c9=1.445305721320277f;

  for(int idx=beg; idx<endp; idx++){
    int e = elist[idx];
    int snd = eidx[e];
    float vx = px - pos[snd*3+0] + shifts[e*3+0];
    float vy = py - pos[snd*3+1] + shifts[e*3+1];
    float vz = pz - pos[snd*3+2] + shifts[e*3+2];
    float r = sqrtf(vx*vx+vy*vy+vz*vz + 1e-12f);
    float invr = 1.f/r;
    float x=vx*invr, y=vy*invr, z=vz*invr;
    float Y[16]; sph16(x,y,z,Y);
    float rs = r*TAB_SCALE;
    int i0 = (int)rs; i0 = i0 < NPTS-2 ? i0 : NPTS-2;
    float fr = rs - (float)i0;
    const float* t0 = w_tab  + i0*64 + lane;
    const float* d0 = dw_tab + i0*64 + lane;
    float w    = t0[0] + fr*(t0[64]-t0[0]);
    float dwdr = d0[0] + fr*(d0[64]-d0[0]);
    float hk = h[(size_t)snd*64+lane];
    float wh = w*hk;
    float gw = 0.f;
    #pragma unroll
    for(int lm=0;lm<16;lm++) gw += gm[lm]*Y[lm];
    gw *= hk;
    float x2=x*x, y2=y*y, z2=z*z;
    float fz1 = 5.f*z2-1.f;
    float gxp = c1*gm[3] + c2*(y*gm[4] + z*gm[7]) + 2.f*c4*x*gm[8]
              + 6.f*c5*x*y*gm[9] + c6*y*z*gm[10] + c7*fz1*gm[13]
              + 2.f*c9*x*z*gm[14] + 3.f*c5*(x2-y2)*gm[15];
    float gyp = c1*gm[1] + c2*(x*gm[4] + z*gm[5]) - 2.f*c4*y*gm[8]
              + 3.f*c5*(x2-y2)*gm[9] + c6*x*z*gm[10] + c7*fz1*gm[11]
              - 2.f*c9*y*z*gm[14] - 6.f*c5*x*y*gm[15];
    float gzp = c1*gm[2] + c2*(y*gm[5] + x*gm[7]) + 6.f*c3*z*gm[6]
              + c6*x*y*gm[10] + 10.f*c7*y*z*gm[11] + c8*(15.f*z2-3.f)*gm[12]
              + 10.f*c7*x*z*gm[13] + c9*(x2-y2)*gm[14];
    float gx = gxp*wh*SQ4PI, gy = gyp*wh*SQ4PI, gz = gzp*wh*SQ4PI;
    float grp = gw*dwdr;
    #pragma unroll
    for(int off=32; off; off>>=1){
      gx  += __shfl_xor(gx,  off, 64);
      gy  += __shfl_xor(gy,  off, 64);
      gz  += __shfl_xor(gz,  off, 64);
      grp += __shfl_xor(grp, off, 64);
    }
    float udot = x*gx + y*gy + z*gz;
    float gvx = grp*x + (gx - udot*x)*invr;
    float gvy = grp*y + (gy - udot*y)*invr;
    float gvz = grp*z + (gz - udot*z)*invr;
    fx -= gvx; fy -= gvy; fz -= gvz;
    if(lane==0){
      atomicAdd(&forces[snd*3+0],  gvx);
      atomicAdd(&forces[snd*3+1],  gvy);
      atomicAdd(&forces[snd*3+2],  gvz);
    }
  }
  if(lane==0){
    atomicAdd(&forces[n*3+0], fx);
    atomicAdd(&forces[n*3+1], fy);
    atomicAdd(&forces[n*3+2], fz);
  }
}

// ---------------- finalize ---------------------------------------------
__global__ void fin_k(const float* __restrict__ e_acc, float* __restrict__ out, int G){
  int g = threadIdx.x;
  if(g < G){
    float e0 = e_acc[2*g], e1 = e_acc[2*g+1];
    out[g] = e0+e1;
    out[G + 2*g] = e0;
    out[G + 2*g+1] = e1;
  }
}

extern "C" void kernel_launch(void* const* d_in, const int* in_sizes, int n_in,
                              void* d_out, int out_size, void* d_ws, size_t ws_size,
                              hipStream_t stream) {
  const float* positions  = (const float*)d_in[0];
  const float* node_attrs = (const float*)d_in[1];
  const float* shifts     = (const float*)d_in[2];
  const float* W_embed    = (const float*)d_in[3];
  const float* at_en      = (const float*)d_in[4];
  const float* W_r1       = (const float*)d_in[5];
  const float* W_r2       = (const float*)d_in[6];
  const float* W_mix      = (const float*)d_in[7];
  const float* W_prod     = (const float*)d_in[8];
  const float* w_ro       = (const float*)d_in[9];
  const int*   edge_index = (const int*)d_in[10];
  const int*   batch      = (const int*)d_in[11];

  int N = in_sizes[0]/3;
  int E = in_sizes[10]/2;
  int G = (out_size - 3*N)/3;

  float* out    = (float*)d_out;
  float* bufA   = (float*)d_ws;                 // N*1024 f32: Ah (f16 pairs) then gA
  float* h      = bufA + (size_t)N*1024;        // N*64
  float* w_tab  = h + (size_t)N*64;             // NPTS*64
  float* dw_tab = w_tab + (size_t)NPTS*64;      // NPTS*64
  unsigned int* gAm = (unsigned int*)(dw_tab + (size_t)NPTS*64); // N*512
  unsigned int* Wpc = gAm + (size_t)N*512;      // 8192
  unsigned int* Wpr = Wpc + 8192;               // 8192
  float* eacc   = (float*)(Wpr + 8192);         // 2G
  int*   deg    = (int*)(eacc + 2*G);           // N
  int*   rowptr = deg + N;                      // N+1
  int*   cursor = rowptr + N + 1;               // N
  int*   elist  = cursor + N;                   // E

  unsigned int* Ah = (unsigned int*)bufA;

  hipMemsetAsync(d_out, 0, (size_t)out_size*sizeof(float), stream);
  hipMemsetAsync(eacc, 0, (size_t)2*G*sizeof(float), stream);
  hipMemsetAsync(deg, 0, (size_t)N*sizeof(int), stream);

  embed_k<<<N, 64, 0, stream>>>(node_attrs, W_embed, at_en, batch, h, eacc, N);
  tab_k<<<NPTS, 64, 0, stream>>>(W_r1, W_r2, w_tab, dw_tab);
  pack_k<<<32, 256, 0, stream>>>(W_mix, Wpc, Wpr);
  count_k<<<(E+255)/256, 256, 0, stream>>>(positions, shifts, edge_index, deg, E);
  scan_k<<<1, 256, 0, stream>>>(deg, rowptr, cursor, N);
  scatter_k<<<(E+255)/256, 256, 0, stream>>>(positions, shifts, edge_index, cursor, elist, E);
  fwd_tab<<<(N+3)/4, 256, 0, stream>>>(positions, shifts, edge_index, h, w_tab, rowptr, elist, Ah, N, E);
  node_fwd<<<1024, 256, 0, stream>>>(Ah, Wpc, W_prod, w_ro, batch, eacc, gAm, N);
  node_bwd<<<1024, 256, 0, stream>>>(gAm, Wpr, bufA, N);
  bwd_tab<<<(N+3)/4, 256, 0, stream>>>(positions, shifts, edge_index, h, w_tab, dw_tab, bufA, rowptr, elist, out + 3*G, N, E);
  fin_k<<<1, 64, 0, stream>>>(eacc, out, G);
}

// Round 12
// 368.613 us; speedup vs baseline: 1.0933x; 1.0933x over previous
//
#include <hip/hip_runtime.h>
#include <cmath>

#define RMAXF 5.0f
#define INV_AVG (1.0f/16.0f)
#define SQ4PI 3.5449077018110318f
#define NPTS 4096
#define TAB_SCALE ((float)(NPTS-1)/RMAXF)

typedef short short8 __attribute__((ext_vector_type(8)));
typedef float f32x4 __attribute__((ext_vector_type(4)));

__device__ __forceinline__ unsigned int bfr(float x){
  unsigned int u = __float_as_uint(x);
  u += 0x7fffu + ((u>>16)&1u);
  return u>>16;
}
__device__ __forceinline__ unsigned int pkbf(float a, float b){
  return bfr(a) | (bfr(b)<<16);
}
__device__ __forceinline__ float unlo(unsigned int u){ return __uint_as_float(u<<16); }
__device__ __forceinline__ float unhi(unsigned int u){ return __uint_as_float(u & 0xffff0000u); }
__device__ __forceinline__ short8 as_s8(uint4 u){ short8 r; __builtin_memcpy(&r,&u,16); return r; }

// l-grouped row index: rows[lm] = O_l + n*(2l+1) + m
__device__ __forceinline__ void node_rows(int n, int O0,int O1,int O2,int O3, int* rows){
  rows[0]=O0+n;
  int r1=O1+n*3;
  rows[1]=r1; rows[2]=r1+1; rows[3]=r1+2;
  int r2=O2+n*5;
  #pragma unroll
  for(int m=0;m<5;m++) rows[4+m]=r2+m;
  int r3=O3+n*7;
  #pragma unroll
  for(int m=0;m<7;m++) rows[9+m]=r3+m;
}

// Real sph harmonics l=0..3 (times sqrt(4pi)) of unit vector (x,y,z)
__device__ __forceinline__ void sph16(float x, float y, float z, float* Y){
  float x2=x*x, y2=y*y, z2=z*z;
  Y[0]=SQ4PI*0.28209479177387814f;
  Y[1]=SQ4PI*0.4886025119029199f*y;
  Y[2]=SQ4PI*0.4886025119029199f*z;
  Y[3]=SQ4PI*0.4886025119029199f*x;
  Y[4]=SQ4PI*1.0925484305920792f*x*y;
  Y[5]=SQ4PI*1.0925484305920792f*y*z;
  Y[6]=SQ4PI*0.31539156525252005f*(3.f*z2-1.f);
  Y[7]=SQ4PI*1.0925484305920792f*x*z;
  Y[8]=SQ4PI*0.5462742152960396f*(x2-y2);
  Y[9]=SQ4PI*0.5900435899266435f*y*(3.f*x2-y2);
  Y[10]=SQ4PI*2.890611442640554f*x*y*z;
  Y[11]=SQ4PI*0.4570457994644658f*y*(5.f*z2-1.f);
  Y[12]=SQ4PI*0.3731763325901154f*z*(5.f*z2-3.f);
  Y[13]=SQ4PI*0.4570457994644658f*x*(5.f*z2-1.f);
  Y[14]=SQ4PI*1.445305721320277f*z*(x2-y2);
  Y[15]=SQ4PI*0.5900435899266435f*x*(x2-3.f*y2);
}

// radial basis ef[8] = bess*fcut and d(ef)/dr (table builder only)
__device__ __forceinline__ void radial(float r, float* ef, float* def){
  const float PI_ = 3.14159265358979323846f;
  const float c = 0.6324555320336759f; // sqrt(2/5)
  float xr = r*(1.0f/RMAXF);
  float x2=xr*xr, x3=x2*xr, x5=x3*x2, x6=x5*xr, x7=x6*xr, x8=x7*xr;
  float fcut = 1.f - 28.f*x6 + 48.f*x7 - 21.f*x8;
  float om = 1.f - xr;
  float dfcut = -168.f*x5*om*om*(1.0f/RMAXF);
  float invr = 1.f/r;
  #pragma unroll
  for(int n=1;n<=8;n++){
    float a = (float)n*PI_*(1.0f/RMAXF);
    float ar = a*r;
    float s, co;
    sincosf(ar, &s, &co);
    float b = c*s*invr;
    ef[n-1] = b*fcut;
    def[n-1] = c*(a*co - s*invr)*invr*fcut + b*dfcut;
  }
}

// ---------------- build radial tables: w(r), dw/dr(r), 64 channels --------
__global__ __launch_bounds__(64) void tab_k(
    const float* __restrict__ W_r1, const float* __restrict__ W_r2,
    float* __restrict__ w_tab, float* __restrict__ dw_tab)
{
  __shared__ float s_sil[64], s_ds[64];
  int p = blockIdx.x, lane = threadIdx.x;
  float r = fmaxf((float)p * (RMAXF/(float)(NPTS-1)), 1e-6f);
  float ef[8], def[8];
  radial(r, ef, def);
  float t = 0.f, dt = 0.f;
  #pragma unroll
  for(int j=0;j<8;j++){ t += ef[j]*W_r1[j*64+lane]; dt += def[j]*W_r1[j*64+lane]; }
  float sig = 1.f/(1.f+expf(-t));
  s_sil[lane] = t*sig;
  s_ds[lane]  = sig*(1.f + t*(1.f-sig))*dt;
  __syncthreads();
  float w = 0.f, dw = 0.f;
  for(int j=0;j<64;j++){
    w  += s_sil[j]*W_r2[j*64+lane];
    dw += s_ds[j] *W_r2[j*64+lane];
  }
  w_tab[p*64+lane]  = w;
  dw_tab[p*64+lane] = dw;
}

// ---------------- node embed: h = attrs @ W_embed, e0 atomic per graph ----
__global__ __launch_bounds__(64) void embed_k(
    const float* __restrict__ attrs, const float* __restrict__ W_embed,
    const float* __restrict__ ae, const int* __restrict__ batch,
    float* __restrict__ h, float* __restrict__ e_acc, int N)
{
  int n = blockIdx.x;
  if(n >= N) return;
  int k = threadIdx.x;
  float acc = 0.f;
  #pragma unroll
  for(int s=0;s<10;s++) acc += attrs[n*10+s]*W_embed[s*64+k];
  h[(size_t)n*64+k] = acc;
  if(k==0){
    float e0 = 0.f;
    #pragma unroll
    for(int s=0;s<10;s++) e0 += attrs[n*10+s]*ae[s];
    atomicAdd(&e_acc[batch[n]*2+0], e0);
  }
}

// ---------------- pack W_mix as bf16 pairs, both orientations -------------
// Wpc[l][c][kp] = (W[l][2kp][c], W[l][2kp+1][c])   (fwd B-frag: pairs along k)
// Wpr[l][k][cp] = (W[l][k][2cp], W[l][k][2cp+1])   (bwd B-frag: W^T, pairs along c)
__global__ void pack_k(const float* __restrict__ W_mix,
                       unsigned int* __restrict__ Wpc,
                       unsigned int* __restrict__ Wpr){
  int i = threadIdx.x + blockIdx.x*blockDim.x;
  if(i < 8192){
    int l = i >> 11, a = (i >> 5) & 63, p = i & 31;
    Wpc[i] = pkbf(W_mix[l*4096 + (2*p)*64 + a], W_mix[l*4096 + (2*p+1)*64 + a]);
    Wpr[i] = pkbf(W_mix[l*4096 + a*64 + 2*p], W_mix[l*4096 + a*64 + 2*p+1]);
  }
}

// ---------------- CSR build over surviving edges (r < RMAX), key = recv ---
__global__ __launch_bounds__(256) void count_k(
    const float* __restrict__ pos, const float* __restrict__ shifts,
    const int* __restrict__ eidx, int* __restrict__ deg, int E)
{
  int e = blockIdx.x*256 + threadIdx.x;
  if(e >= E) return;
  int snd = eidx[e], rcv = eidx[E+e];
  float vx = pos[rcv*3+0]-pos[snd*3+0]+shifts[e*3+0];
  float vy = pos[rcv*3+1]-pos[snd*3+1]+shifts[e*3+1];
  float vz = pos[rcv*3+2]-pos[snd*3+2]+shifts[e*3+2];
  float r2 = vx*vx+vy*vy+vz*vz + 1e-12f;
  if(r2 < RMAXF*RMAXF) atomicAdd(&deg[rcv], 1);
}

__global__ __launch_bounds__(256) void scan_k(
    const int* __restrict__ deg, int* __restrict__ rowptr,
    int* __restrict__ cursor, int N)
{
  __shared__ int part[256];
  int tid = threadIdx.x;
  int chunk = (N + 255) / 256;
  int begin = tid*chunk, end = begin+chunk < N ? begin+chunk : N;
  int s = 0;
  for(int i=begin;i<end;i++) s += deg[i];
  part[tid] = s;
  __syncthreads();
  for(int off=1; off<256; off<<=1){
    int t = (tid >= off) ? part[tid-off] : 0;
    __syncthreads();
    part[tid] += t;
    __syncthreads();
  }
  int run = part[tid] - s;   // exclusive prefix of this thread's chunk
  for(int i=begin;i<end;i++){
    rowptr[i] = run; cursor[i] = run; run += deg[i];
  }
  if(tid == 255) rowptr[N] = part[255];
}

__global__ __launch_bounds__(256) void scatter_k(
    const float* __restrict__ pos, const float* __restrict__ shifts,
    const int* __restrict__ eidx, int* __restrict__ cursor,
    int* __restrict__ elist, int E)
{
  int e = blockIdx.x*256 + threadIdx.x;
  if(e >= E) return;
  int snd = eidx[e], rcv = eidx[E+e];
  float vx = pos[rcv*3+0]-pos[snd*3+0]+shifts[e*3+0];
  float vy = pos[rcv*3+1]-pos[snd*3+1]+shifts[e*3+1];
  float vz = pos[rcv*3+2]-pos[snd*3+2]+shifts[e*3+2];
  float r2 = vx*vx+vy*vy+vz*vz + 1e-12f;
  if(r2 < RMAXF*RMAXF){
    int p = atomicAdd(&cursor[rcv], 1);
    elist[p] = e;
  }
}

// ---------------- edge forward: one wave per node; A in l-grouped bf16 ----
__global__ __launch_bounds__(256) void fwd_tab(
    const float* __restrict__ pos, const float* __restrict__ shifts,
    const int* __restrict__ eidx, const float* __restrict__ h,
    const float* __restrict__ w_tab,
    const int* __restrict__ rowptr, const int* __restrict__ elist,
    unsigned int* __restrict__ AhL, int N, int E,
    int O0,int O1,int O2,int O3)
{
  int tid = threadIdx.x, ws4 = tid >> 6, lane = tid & 63;
  int n = blockIdx.x*4 + ws4;
  if(n >= N) return;
  int beg = rowptr[n], endp = rowptr[n+1];
  float acc[16];
  #pragma unroll
  for(int lm=0;lm<16;lm++) acc[lm] = 0.f;
  float px = pos[n*3+0], py = pos[n*3+1], pz = pos[n*3+2];
  for(int idx=beg; idx<endp; idx++){
    int e = elist[idx];
    int snd = eidx[e];
    float vx = px - pos[snd*3+0] + shifts[e*3+0];
    float vy = py - pos[snd*3+1] + shifts[e*3+1];
    float vz = pz - pos[snd*3+2] + shifts[e*3+2];
    float r = sqrtf(vx*vx+vy*vy+vz*vz + 1e-12f);
    float invr = 1.f/r;
    float Y[16]; sph16(vx*invr, vy*invr, vz*invr, Y);
    float rs = r*TAB_SCALE;
    int i0 = (int)rs; i0 = i0 < NPTS-2 ? i0 : NPTS-2;
    float fr = rs - (float)i0;
    const float* t0 = w_tab + i0*64 + lane;
    float w0 = t0[0], w1 = t0[64];
    float w = w0 + fr*(w1-w0);
    float wh = w * h[(size_t)snd*64+lane] * INV_AVG;
    #pragma unroll
    for(int lm=0;lm<16;lm++) acc[lm] += wh*Y[lm];
  }
  int rows[16]; node_rows(n,O0,O1,O2,O3,rows);
  #pragma unroll
  for(int lm=0;lm<16;lm++){
    float nb = __shfl_xor(acc[lm], 1, 64);
    if(!(lane&1)) AhL[(size_t)rows[lm]*32 + (lane>>1)] = pkbf(acc[lm], nb);
  }
}

// ---------------- node GEMM: C[M x 64] = A[M x 64] @ B_l[64 x 64] ---------
// One 16-row tile per wave, 8x mfma_f32_16x16x32_bf16, all bf16-packed.
// A-frag: row=lane&15, k=8*(lane>>4)+i. B-frag: col=lane&15, k=8*(lane>>4)+i.
// C/D: col=lane&15, row=(lane>>4)*4+r  [m89-verified].
__global__ __launch_bounds__(256) void gemm_k(
    const unsigned int* __restrict__ Asrc,  // [Mtot][32] bf16-pair rows
    const unsigned int* __restrict__ Wsrc,  // [4][64][32] bf16 pairs along K
    unsigned int* __restrict__ Cdst,        // [Mtot][32] bf16-pair rows
    int t1, int t2, int t3, int T)
{
  int wv = threadIdx.x >> 6, lane = threadIdx.x & 63;
  int lrow = lane & 15, lblk = lane >> 4;
  for(int t = blockIdx.x*4 + wv; t < T; t += gridDim.x*4){
    int l = (t < t1) ? 0 : ((t < t2) ? 1 : ((t < t3) ? 2 : 3));
    const unsigned int* Wb = Wsrc + l*2048;
    int rowbase = t*16;
    const uint4* arow = (const uint4*)(Asrc + (size_t)rowbase*32);
    short8 aF0 = as_s8(arow[lrow*8 + lblk]);        // k 0..31
    short8 aF1 = as_s8(arow[lrow*8 + 4 + lblk]);    // k 32..63
    #pragma unroll
    for(int j=0;j<4;j++){
      int c = j*16 + lrow;
      uint4 b0u = *(const uint4*)(Wb + c*32 + lblk*4);
      uint4 b1u = *(const uint4*)(Wb + c*32 + 16 + lblk*4);
      f32x4 acc = {0.f,0.f,0.f,0.f};
      acc = __builtin_amdgcn_mfma_f32_16x16x32_bf16(aF0, as_s8(b0u), acc, 0,0,0);
      acc = __builtin_amdgcn_mfma_f32_16x16x32_bf16(aF1, as_s8(b1u), acc, 0,0,0);
      #pragma unroll
      for(int r=0;r<4;r++){
        float v = acc[r];
        float nb = __shfl_xor(v, 1, 64);
        if(!(lane&1)){
          int grow = rowbase + lblk*4 + r;
          Cdst[(size_t)grow*32 + j*8 + (lrow>>1)] = pkbf(v, nb);
        }
      }
    }
  }
}

// ---------------- node nonlinear middle: s, B, e1, gAm --------------------
__global__ __launch_bounds__(256) void mid_k(
    const unsigned int* __restrict__ AmH,
    const float* __restrict__ W_prod, const float* __restrict__ w_ro,
    const int* __restrict__ batch, float* __restrict__ e_acc,
    unsigned int* __restrict__ gAmL, int N, int O0,int O1,int O2,int O3)
{
  int wv = threadIdx.x >> 6, lane = threadIdx.x & 63;
  int n = blockIdx.x*4 + wv;
  if(n >= N) return;
  int rows[16]; node_rows(n,O0,O1,O2,O3,rows);
  float am[16];
  #pragma unroll
  for(int lm=0;lm<16;lm++){
    unsigned int u = AmH[(size_t)rows[lm]*32 + (lane>>1)];
    am[lm] = (lane&1) ? unhi(u) : unlo(u);
  }
  float s_ = 0.f;
  #pragma unroll
  for(int lm=0;lm<16;lm++) s_ += am[lm]*am[lm];
  float a0_ = am[0];
  float wp0 = W_prod[lane], wp1 = W_prod[64+lane], wp2 = W_prod[128+lane];
  float wr = w_ro[lane];
  float Bv = wp0*a0_ + wp1*s_ + wp2*a0_*s_;
  float v = Bv*wr;
  #pragma unroll
  for(int off=32; off; off>>=1) v += __shfl_xor(v, off, 64);
  if(lane==0) atomicAdd(&e_acc[batch[n]*2+1], v);
  float gs = wr*(wp1 + wp2*a0_);
  #pragma unroll
  for(int lm=0;lm<16;lm++){
    float g = gs*2.f*am[lm];
    if(lm==0) g += wr*(wp0 + wp2*s_);
    float nb = __shfl_xor(g, 1, 64);
    if(!(lane&1)) gAmL[(size_t)rows[lm]*32 + (lane>>1)] = pkbf(g, nb);
  }
}

// ---------------- edge backward: one wave per node, table lookup ----------
__global__ __launch_bounds__(256) void bwd_tab(
    const float* __restrict__ pos, const float* __restrict__ shifts,
    const int* __restrict__ eidx, const float* __restrict__ h,
    const float* __restrict__ w_tab, const float* __restrict__ dw_tab,
    const unsigned int* __restrict__ gAH,
    const int* __restrict__ rowptr, const int* __restrict__ elist,
    float* __restrict__ forces, int N, int E,
    int O0,int O1,int O2,int O3)
{
  int tid = threadIdx.x, ws4 = tid >> 6, lane = tid & 63;
  int n = blockIdx.x*4 + ws4;
  if(n >= N) return;
  int beg = rowptr[n], endp = rowptr[n+1];
  if(beg == endp) return;
  int rows[16]; node_rows(n,O0,O1,O2,O3,rows);
  float gm[16];
  #pragma unroll
  for(int lm=0;lm<16;lm++){
    unsigned int u = gAH[(size_t)rows[lm]*32 + (lane>>1)];
    gm[lm] = ((lane&1) ? unhi(u) : unlo(u)) * INV_AVG;
  }
  float px = pos[n*3+0], py = pos[n*3+1], pz = pos[n*3+2];
  float fx=0.f, fy=0.f, fz=0.f;
  const float c1=0.4886025119029199f, c2=1.0925484305920792f, c3=0.31539156525252005f;
  const float c4=0.5462742152960396f, c5=0.5900435899266435f, c6=2.890611442640554f;
  const float c7=0.4570457994644658f, c8=0.3731763325901154f, c9=1.445305721320277f;

  for(int idx=beg; idx<endp; idx++){
    int e = elist[idx];
    int snd = eidx[e];
    float vx = px - pos[snd*3+0] + shifts[e*3+0];
    float vy = py - pos[snd*3+1] + shifts[e*3+1];
    float vz = pz - pos[snd*3+2] + shifts[e*3+2];
    float r = sqrtf(vx*vx+vy*vy+vz*vz + 1e-12f);
    float invr = 1.f/r;
    float x=vx*invr, y=vy*invr, z=vz*invr;
    float Y[16]; sph16(x,y,z,Y);
    float rs = r*TAB_SCALE;
    int i0 = (int)rs; i0 = i0 < NPTS-2 ? i0 : NPTS-2;
    float fr = rs - (float)i0;
    const float* t0 = w_tab  + i0*64 + lane;
    const float* d0 = dw_tab + i0*64 + lane;
    float w    = t0[0] + fr*(t0[64]-t0[0]);
    float dwdr = d0[0] + fr*(d0[64]-d0[0]);
    float hk = h[(size_t)snd*64+lane];
    float wh = w*hk;
    float gw = 0.f;
    #pragma unroll
    for(int lm=0;lm<16;lm++) gw += gm[lm]*Y[lm];
    gw *= hk;
    float x2=x*x, y2=y*y, z2=z*z;
    float fz1 = 5.f*z2-1.f;
    float gxp = c1*gm[3] + c2*(y*gm[4] + z*gm[7]) + 2.f*c4*x*gm[8]
              + 6.f*c5*x*y*gm[9] + c6*y*z*gm[10] + c7*fz1*gm[13]
              + 2.f*c9*x*z*gm[14] + 3.f*c5*(x2-y2)*gm[15];
    float gyp = c1*gm[1] + c2*(x*gm[4] + z*gm[5]) - 2.f*c4*y*gm[8]
              + 3.f*c5*(x2-y2)*gm[9] + c6*x*z*gm[10] + c7*fz1*gm[11]
              - 2.f*c9*y*z*gm[14] - 6.f*c5*x*y*gm[15];
    float gzp = c1*gm[2] + c2*(y*gm[5] + x*gm[7]) + 6.f*c3*z*gm[6]
              + c6*x*y*gm[10] + 10.f*c7*y*z*gm[11] + c8*(15.f*z2-3.f)*gm[12]
              + 10.f*c7*x*z*gm[13] + c9*(x2-y2)*gm[14];
    float gx = gxp*wh*SQ4PI, gy = gyp*wh*SQ4PI, gz = gzp*wh*SQ4PI;
    float grp = gw*dwdr;
    #pragma unroll
    for(int off=32; off; off>>=1){
      gx  += __shfl_xor(gx,  off, 64);
      gy  += __shfl_xor(gy,  off, 64);
      gz  += __shfl_xor(gz,  off, 64);
      grp += __shfl_xor(grp, off, 64);
    }
    float udot = x*gx + y*gy + z*gz;
    float gvx = grp*x + (gx - udot*x)*invr;
    float gvy = grp*y + (gy - udot*y)*invr;
    float gvz = grp*z + (gz - udot*z)*invr;
    fx -= gvx; fy -= gvy; fz -= gvz;
    if(lane==0){
      atomicAdd(&forces[snd*3+0],  gvx);
      atomicAdd(&forces[snd*3+1],  gvy);
      atomicAdd(&forces[snd*3+2],  gvz);
    }
  }
  if(lane==0){
    atomicAdd(&forces[n*3+0], fx);
    atomicAdd(&forces[n*3+1], fy);
    atomicAdd(&forces[n*3+2], fz);
  }
}

// ---------------- finalize ---------------------------------------------
__global__ void fin_k(const float* __restrict__ e_acc, float* __restrict__ out, int G){
  int g = threadIdx.x;
  if(g < G){
    float e0 = e_acc[2*g], e1 = e_acc[2*g+1];
    out[g] = e0+e1;
    out[G + 2*g] = e0;
    out[G + 2*g+1] = e1;
  }
}

extern "C" void kernel_launch(void* const* d_in, const int* in_sizes, int n_in,
                              void* d_out, int out_size, void* d_ws, size_t ws_size,
                              hipStream_t stream) {
  const float* positions  = (const float*)d_in[0];
  const float* node_attrs = (const float*)d_in[1];
  const float* shifts     = (const float*)d_in[2];
  const float* W_embed    = (const float*)d_in[3];
  const float* at_en      = (const float*)d_in[4];
  const float* W_r1       = (const float*)d_in[5];
  const float* W_r2       = (const float*)d_in[6];
  const float* W_mix      = (const float*)d_in[7];
  const float* W_prod     = (const float*)d_in[8];
  const float* w_ro       = (const float*)d_in[9];
  const int*   edge_index = (const int*)d_in[10];
  const int*   batch      = (const int*)d_in[11];

  int N = in_sizes[0]/3;
  int E = in_sizes[10]/2;
  int G = (out_size - 3*N)/3;

  // l-grouped rows, each region padded to multiple of 16
  int Mp0 = (N   + 15) & ~15;
  int Mp1 = (3*N + 15) & ~15;
  int Mp2 = (5*N + 15) & ~15;
  int Mp3 = (7*N + 15) & ~15;
  int O0 = 0, O1 = Mp0, O2 = O1 + Mp1, O3 = O2 + Mp2;
  int Mp = O3 + Mp3;
  int T   = Mp  / 16;
  int tt1 = Mp0 / 16;
  int tt2 = tt1 + Mp1/16;
  int tt3 = tt2 + Mp2/16;

  float* out = (float*)d_out;
  unsigned int* AhL  = (unsigned int*)d_ws;       // [Mp][32] bf16 pairs; reused as gAH
  unsigned int* AmH  = AhL + (size_t)Mp*32;       // [Mp][32]
  unsigned int* gAmL = AmH + (size_t)Mp*32;       // [Mp][32]
  float* h      = (float*)(gAmL + (size_t)Mp*32); // N*64
  float* w_tab  = h + (size_t)N*64;               // NPTS*64
  float* dw_tab = w_tab + (size_t)NPTS*64;        // NPTS*64
  unsigned int* Wpc = (unsigned int*)(dw_tab + (size_t)NPTS*64); // 8192
  unsigned int* Wpr = Wpc + 8192;                 // 8192
  float* eacc   = (float*)(Wpr + 8192);           // 2G
  int*   deg    = (int*)(eacc + 2*G);             // N
  int*   rowptr = deg + N;                        // N+1
  int*   cursor = rowptr + N + 1;                 // N
  int*   elist  = cursor + N;                     // E

  hipMemsetAsync(d_out, 0, (size_t)out_size*sizeof(float), stream);
  hipMemsetAsync(eacc, 0, (size_t)2*G*sizeof(float), stream);
  hipMemsetAsync(deg, 0, (size_t)N*sizeof(int), stream);

  embed_k<<<N, 64, 0, stream>>>(node_attrs, W_embed, at_en, batch, h, eacc, N);
  tab_k<<<NPTS, 64, 0, stream>>>(W_r1, W_r2, w_tab, dw_tab);
  pack_k<<<32, 256, 0, stream>>>(W_mix, Wpc, Wpr);
  count_k<<<(E+255)/256, 256, 0, stream>>>(positions, shifts, edge_index, deg, E);
  scan_k<<<1, 256, 0, stream>>>(deg, rowptr, cursor, N);
  scatter_k<<<(E+255)/256, 256, 0, stream>>>(positions, shifts, edge_index, cursor, elist, E);
  fwd_tab<<<(N+3)/4, 256, 0, stream>>>(positions, shifts, edge_index, h, w_tab,
                                       rowptr, elist, AhL, N, E, O0,O1,O2,O3);
  gemm_k<<<(T+3)/4, 256, 0, stream>>>(AhL, Wpc, AmH, tt1, tt2, tt3, T);
  mid_k<<<(N+3)/4, 256, 0, stream>>>(AmH, W_prod, w_ro, batch, eacc, gAmL, N, O0,O1,O2,O3);
  gemm_k<<<(T+3)/4, 256, 0, stream>>>(gAmL, Wpr, AhL, tt1, tt2, tt3, T);  // gAH := AhL
  bwd_tab<<<(N+3)/4, 256, 0, stream>>>(positions, shifts, edge_index, h, w_tab, dw_tab,
                                       AhL, rowptr, elist, out + 3*G, N, E, O0,O1,O2,O3);
  fin_k<<<1, 64, 0, stream>>>(eacc, out, G);
}

// Round 13
// 193.269 us; speedup vs baseline: 2.0853x; 1.9073x over previous
//
#include <hip/hip_runtime.h>
#include <cmath>

#define RMAXF 5.0f
#define INV_AVG (1.0f/16.0f)
#define SQ4PI 3.5449077018110318f
#define NPTS 4096
#define TAB_SCALE ((float)(NPTS-1)/RMAXF)

typedef short short8 __attribute__((ext_vector_type(8)));
typedef float f32x4 __attribute__((ext_vector_type(4)));

__device__ __forceinline__ unsigned int bfr(float x){
  unsigned int u = __float_as_uint(x);
  u += 0x7fffu + ((u>>16)&1u);
  return u>>16;
}
__device__ __forceinline__ unsigned int pkbf(float a, float b){
  return bfr(a) | (bfr(b)<<16);
}
__device__ __forceinline__ float unlo(unsigned int u){ return __uint_as_float(u<<16); }
__device__ __forceinline__ float unhi(unsigned int u){ return __uint_as_float(u & 0xffff0000u); }
__device__ __forceinline__ short8 as_s8(uint4 u){ short8 r; __builtin_memcpy(&r,&u,16); return r; }

// l-grouped row index: rows[lm] = O_l + n*(2l+1) + m
__device__ __forceinline__ void node_rows(int n, int O0,int O1,int O2,int O3, int* rows){
  rows[0]=O0+n;
  int r1=O1+n*3;
  rows[1]=r1; rows[2]=r1+1; rows[3]=r1+2;
  int r2=O2+n*5;
  #pragma unroll
  for(int m=0;m<5;m++) rows[4+m]=r2+m;
  int r3=O3+n*7;
  #pragma unroll
  for(int m=0;m<7;m++) rows[9+m]=r3+m;
}

// Real sph harmonics l=0..3 (times sqrt(4pi)) of unit vector (x,y,z)
__device__ __forceinline__ void sph16(float x, float y, float z, float* Y){
  float x2=x*x, y2=y*y, z2=z*z;
  Y[0]=SQ4PI*0.28209479177387814f;
  Y[1]=SQ4PI*0.4886025119029199f*y;
  Y[2]=SQ4PI*0.4886025119029199f*z;
  Y[3]=SQ4PI*0.4886025119029199f*x;
  Y[4]=SQ4PI*1.0925484305920792f*x*y;
  Y[5]=SQ4PI*1.0925484305920792f*y*z;
  Y[6]=SQ4PI*0.31539156525252005f*(3.f*z2-1.f);
  Y[7]=SQ4PI*1.0925484305920792f*x*z;
  Y[8]=SQ4PI*0.5462742152960396f*(x2-y2);
  Y[9]=SQ4PI*0.5900435899266435f*y*(3.f*x2-y2);
  Y[10]=SQ4PI*2.890611442640554f*x*y*z;
  Y[11]=SQ4PI*0.4570457994644658f*y*(5.f*z2-1.f);
  Y[12]=SQ4PI*0.3731763325901154f*z*(5.f*z2-3.f);
  Y[13]=SQ4PI*0.4570457994644658f*x*(5.f*z2-1.f);
  Y[14]=SQ4PI*1.445305721320277f*z*(x2-y2);
  Y[15]=SQ4PI*0.5900435899266435f*x*(x2-3.f*y2);
}

// radial basis ef[8] = bess*fcut and d(ef)/dr (table builder only)
__device__ __forceinline__ void radial(float r, float* ef, float* def){
  const float PI_ = 3.14159265358979323846f;
  const float c = 0.6324555320336759f; // sqrt(2/5)
  float xr = r*(1.0f/RMAXF);
  float x2=xr*xr, x3=x2*xr, x5=x3*x2, x6=x5*xr, x7=x6*xr, x8=x7*xr;
  float fcut = 1.f - 28.f*x6 + 48.f*x7 - 21.f*x8;
  float om = 1.f - xr;
  float dfcut = -168.f*x5*om*om*(1.0f/RMAXF);
  float invr = 1.f/r;
  #pragma unroll
  for(int n=1;n<=8;n++){
    float a = (float)n*PI_*(1.0f/RMAXF);
    float ar = a*r;
    float s, co;
    sincosf(ar, &s, &co);
    float b = c*s*invr;
    ef[n-1] = b*fcut;
    def[n-1] = c*(a*co - s*invr)*invr*fcut + b*dfcut;
  }
}

// ---------------- build radial tables: w(r), dw/dr(r), 64 channels --------
__global__ __launch_bounds__(64) void tab_k(
    const float* __restrict__ W_r1, const float* __restrict__ W_r2,
    float* __restrict__ w_tab, float* __restrict__ dw_tab)
{
  __shared__ float s_sil[64], s_ds[64];
  int p = blockIdx.x, lane = threadIdx.x;
  float r = fmaxf((float)p * (RMAXF/(float)(NPTS-1)), 1e-6f);
  float ef[8], def[8];
  radial(r, ef, def);
  float t = 0.f, dt = 0.f;
  #pragma unroll
  for(int j=0;j<8;j++){ t += ef[j]*W_r1[j*64+lane]; dt += def[j]*W_r1[j*64+lane]; }
  float sig = 1.f/(1.f+expf(-t));
  s_sil[lane] = t*sig;
  s_ds[lane]  = sig*(1.f + t*(1.f-sig))*dt;
  __syncthreads();
  float w = 0.f, dw = 0.f;
  for(int j=0;j<64;j++){
    w  += s_sil[j]*W_r2[j*64+lane];
    dw += s_ds[j] *W_r2[j*64+lane];
  }
  w_tab[p*64+lane]  = w;
  dw_tab[p*64+lane] = dw;
}

// ---------------- node embed: h = attrs @ W_embed; e0 -> per-node buffer --
__global__ __launch_bounds__(64) void embed_k(
    const float* __restrict__ attrs, const float* __restrict__ W_embed,
    const float* __restrict__ ae, const int* __restrict__ batch,
    float* __restrict__ h, float* __restrict__ node_e, int N)
{
  int n = blockIdx.x;
  if(n >= N) return;
  int k = threadIdx.x;
  float acc = 0.f;
  #pragma unroll
  for(int s=0;s<10;s++) acc += attrs[n*10+s]*W_embed[s*64+k];
  h[(size_t)n*64+k] = acc;
  if(k==0){
    float e0 = 0.f;
    #pragma unroll
    for(int s=0;s<10;s++) e0 += attrs[n*10+s]*ae[s];
    node_e[2*n] = e0;   // no atomic
  }
}

// ---------------- pack W_mix as bf16 pairs, both orientations -------------
__global__ void pack_k(const float* __restrict__ W_mix,
                       unsigned int* __restrict__ Wpc,
                       unsigned int* __restrict__ Wpr){
  int i = threadIdx.x + blockIdx.x*blockDim.x;
  if(i < 8192){
    int l = i >> 11, a = (i >> 5) & 63, p = i & 31;
    Wpc[i] = pkbf(W_mix[l*4096 + (2*p)*64 + a], W_mix[l*4096 + (2*p+1)*64 + a]);
    Wpr[i] = pkbf(W_mix[l*4096 + a*64 + 2*p], W_mix[l*4096 + a*64 + 2*p+1]);
  }
}

// ---------------- CSR build over surviving edges (r < RMAX), key = recv ---
__global__ __launch_bounds__(256) void count_k(
    const float* __restrict__ pos, const float* __restrict__ shifts,
    const int* __restrict__ eidx, int* __restrict__ deg, int E)
{
  int e = blockIdx.x*256 + threadIdx.x;
  if(e >= E) return;
  int snd = eidx[e], rcv = eidx[E+e];
  float vx = pos[rcv*3+0]-pos[snd*3+0]+shifts[e*3+0];
  float vy = pos[rcv*3+1]-pos[snd*3+1]+shifts[e*3+1];
  float vz = pos[rcv*3+2]-pos[snd*3+2]+shifts[e*3+2];
  float r2 = vx*vx+vy*vy+vz*vz + 1e-12f;
  if(r2 < RMAXF*RMAXF) atomicAdd(&deg[rcv], 1);
}

__global__ __launch_bounds__(256) void scan_k(
    const int* __restrict__ deg, int* __restrict__ rowptr,
    int* __restrict__ cursor, int N)
{
  __shared__ int part[256];
  int tid = threadIdx.x;
  int chunk = (N + 255) / 256;
  int begin = tid*chunk, end = begin+chunk < N ? begin+chunk : N;
  int s = 0;
  for(int i=begin;i<end;i++) s += deg[i];
  part[tid] = s;
  __syncthreads();
  for(int off=1; off<256; off<<=1){
    int t = (tid >= off) ? part[tid-off] : 0;
    __syncthreads();
    part[tid] += t;
    __syncthreads();
  }
  int run = part[tid] - s;   // exclusive prefix of this thread's chunk
  for(int i=begin;i<end;i++){
    rowptr[i] = run; cursor[i] = run; run += deg[i];
  }
  if(tid == 255) rowptr[N] = part[255];
}

__global__ __launch_bounds__(256) void scatter_k(
    const float* __restrict__ pos, const float* __restrict__ shifts,
    const int* __restrict__ eidx, int* __restrict__ cursor,
    int* __restrict__ elist, int E)
{
  int e = blockIdx.x*256 + threadIdx.x;
  if(e >= E) return;
  int snd = eidx[e], rcv = eidx[E+e];
  float vx = pos[rcv*3+0]-pos[snd*3+0]+shifts[e*3+0];
  float vy = pos[rcv*3+1]-pos[snd*3+1]+shifts[e*3+1];
  float vz = pos[rcv*3+2]-pos[snd*3+2]+shifts[e*3+2];
  float r2 = vx*vx+vy*vy+vz*vz + 1e-12f;
  if(r2 < RMAXF*RMAXF){
    int p = atomicAdd(&cursor[rcv], 1);
    elist[p] = e;
  }
}

// ---------------- edge forward: one wave per node; A in l-grouped bf16 ----
__global__ __launch_bounds__(256) void fwd_tab(
    const float* __restrict__ pos, const float* __restrict__ shifts,
    const int* __restrict__ eidx, const float* __restrict__ h,
    const float* __restrict__ w_tab,
    const int* __restrict__ rowptr, const int* __restrict__ elist,
    unsigned int* __restrict__ AhL, int N, int E,
    int O0,int O1,int O2,int O3)
{
  int tid = threadIdx.x, ws4 = tid >> 6, lane = tid & 63;
  int n = blockIdx.x*4 + ws4;
  if(n >= N) return;
  int beg = rowptr[n], endp = rowptr[n+1];
  float acc[16];
  #pragma unroll
  for(int lm=0;lm<16;lm++) acc[lm] = 0.f;
  float px = pos[n*3+0], py = pos[n*3+1], pz = pos[n*3+2];
  for(int idx=beg; idx<endp; idx++){
    int e = elist[idx];
    int snd = eidx[e];
    float vx = px - pos[snd*3+0] + shifts[e*3+0];
    float vy = py - pos[snd*3+1] + shifts[e*3+1];
    float vz = pz - pos[snd*3+2] + shifts[e*3+2];
    float r = sqrtf(vx*vx+vy*vy+vz*vz + 1e-12f);
    float invr = 1.f/r;
    float Y[16]; sph16(vx*invr, vy*invr, vz*invr, Y);
    float rs = r*TAB_SCALE;
    int i0 = (int)rs; i0 = i0 < NPTS-2 ? i0 : NPTS-2;
    float fr = rs - (float)i0;
    const float* t0 = w_tab + i0*64 + lane;
    float w0 = t0[0], w1 = t0[64];
    float w = w0 + fr*(w1-w0);
    float wh = w * h[(size_t)snd*64+lane] * INV_AVG;
    #pragma unroll
    for(int lm=0;lm<16;lm++) acc[lm] += wh*Y[lm];
  }
  int rows[16]; node_rows(n,O0,O1,O2,O3,rows);
  #pragma unroll
  for(int lm=0;lm<16;lm++){
    float nb = __shfl_xor(acc[lm], 1, 64);
    if(!(lane&1)) AhL[(size_t)rows[lm]*32 + (lane>>1)] = pkbf(acc[lm], nb);
  }
}

// ---------------- node GEMM: C[M x 64] = A[M x 64] @ B_l[64 x 64] ---------
__global__ __launch_bounds__(256) void gemm_k(
    const unsigned int* __restrict__ Asrc,  // [Mtot][32] bf16-pair rows
    const unsigned int* __restrict__ Wsrc,  // [4][64][32] bf16 pairs along K
    unsigned int* __restrict__ Cdst,        // [Mtot][32] bf16-pair rows
    int t1, int t2, int t3, int T)
{
  int wv = threadIdx.x >> 6, lane = threadIdx.x & 63;
  int lrow = lane & 15, lblk = lane >> 4;
  for(int t = blockIdx.x*4 + wv; t < T; t += gridDim.x*4){
    int l = (t < t1) ? 0 : ((t < t2) ? 1 : ((t < t3) ? 2 : 3));
    const unsigned int* Wb = Wsrc + l*2048;
    int rowbase = t*16;
    const uint4* arow = (const uint4*)(Asrc + (size_t)rowbase*32);
    short8 aF0 = as_s8(arow[lrow*8 + lblk]);        // k 0..31
    short8 aF1 = as_s8(arow[lrow*8 + 4 + lblk]);    // k 32..63
    #pragma unroll
    for(int j=0;j<4;j++){
      int c = j*16 + lrow;
      uint4 b0u = *(const uint4*)(Wb + c*32 + lblk*4);
      uint4 b1u = *(const uint4*)(Wb + c*32 + 16 + lblk*4);
      f32x4 acc = {0.f,0.f,0.f,0.f};
      acc = __builtin_amdgcn_mfma_f32_16x16x32_bf16(aF0, as_s8(b0u), acc, 0,0,0);
      acc = __builtin_amdgcn_mfma_f32_16x16x32_bf16(aF1, as_s8(b1u), acc, 0,0,0);
      #pragma unroll
      for(int r=0;r<4;r++){
        float v = acc[r];
        float nb = __shfl_xor(v, 1, 64);
        if(!(lane&1)){
          int grow = rowbase + lblk*4 + r;
          Cdst[(size_t)grow*32 + j*8 + (lrow>>1)] = pkbf(v, nb);
        }
      }
    }
  }
}

// ---------------- node nonlinear middle: s, B, e1, gAm --------------------
__global__ __launch_bounds__(256) void mid_k(
    const unsigned int* __restrict__ AmH,
    const float* __restrict__ W_prod, const float* __restrict__ w_ro,
    float* __restrict__ node_e,
    unsigned int* __restrict__ gAmL, int N, int O0,int O1,int O2,int O3)
{
  int wv = threadIdx.x >> 6, lane = threadIdx.x & 63;
  int n = blockIdx.x*4 + wv;
  if(n >= N) return;
  int rows[16]; node_rows(n,O0,O1,O2,O3,rows);
  float am[16];
  #pragma unroll
  for(int lm=0;lm<16;lm++){
    unsigned int u = AmH[(size_t)rows[lm]*32 + (lane>>1)];
    am[lm] = (lane&1) ? unhi(u) : unlo(u);
  }
  float s_ = 0.f;
  #pragma unroll
  for(int lm=0;lm<16;lm++) s_ += am[lm]*am[lm];
  float a0_ = am[0];
  float wp0 = W_prod[lane], wp1 = W_prod[64+lane], wp2 = W_prod[128+lane];
  float wr = w_ro[lane];
  float Bv = wp0*a0_ + wp1*s_ + wp2*a0_*s_;
  float v = Bv*wr;
  #pragma unroll
  for(int off=32; off; off>>=1) v += __shfl_xor(v, off, 64);
  if(lane==0) node_e[2*n+1] = v;   // no atomic
  float gs = wr*(wp1 + wp2*a0_);
  #pragma unroll
  for(int lm=0;lm<16;lm++){
    float g = gs*2.f*am[lm];
    if(lm==0) g += wr*(wp0 + wp2*s_);
    float nb = __shfl_xor(g, 1, 64);
    if(!(lane&1)) gAmL[(size_t)rows[lm]*32 + (lane>>1)] = pkbf(g, nb);
  }
}

// ---------------- per-graph energy reduction (few atomics) ----------------
__global__ __launch_bounds__(256) void ered_k(
    const float* __restrict__ node_e, const int* __restrict__ batch,
    float* __restrict__ e_acc, int N, int G)
{
  __shared__ float sE[64];
  int tid = threadIdx.x;
  if(tid < 2*G) sE[tid] = 0.f;
  __syncthreads();
  for(int i = blockIdx.x*256 + tid; i < N; i += gridDim.x*256){
    int g = batch[i];
    atomicAdd(&sE[2*g],   node_e[2*i]);
    atomicAdd(&sE[2*g+1], node_e[2*i+1]);
  }
  __syncthreads();
  if(tid < 2*G){
    float v = sE[tid];
    if(v != 0.f) atomicAdd(&e_acc[tid], v);
  }
}

// ---------------- edge backward: one wave per node, table lookup ----------
__global__ __launch_bounds__(256) void bwd_tab(
    const float* __restrict__ pos, const float* __restrict__ shifts,
    const int* __restrict__ eidx, const float* __restrict__ h,
    const float* __restrict__ w_tab, const float* __restrict__ dw_tab,
    const unsigned int* __restrict__ gAH,
    const int* __restrict__ rowptr, const int* __restrict__ elist,
    float* __restrict__ forces, int N, int E,
    int O0,int O1,int O2,int O3)
{
  int tid = threadIdx.x, ws4 = tid >> 6, lane = tid & 63;
  int n = blockIdx.x*4 + ws4;
  if(n >= N) return;
  int beg = rowptr[n], endp = rowptr[n+1];
  if(beg == endp) return;
  int rows[16]; node_rows(n,O0,O1,O2,O3,rows);
  float gm[16];
  #pragma unroll
  for(int lm=0;lm<16;lm++){
    unsigned int u = gAH[(size_t)rows[lm]*32 + (lane>>1)];
    gm[lm] = ((lane&1) ? unhi(u) : unlo(u)) * INV_AVG;
  }
  float px = pos[n*3+0], py = pos[n*3+1], pz = pos[n*3+2];
  float fx=0.f, fy=0.f, fz=0.f;
  const float c1=0.4886025119029199f, c2=1.0925484305920792f, c3=0.31539156525252005f;
  const float c4=0.5462742152960396f, c5=0.5900435899266435f, c6=2.890611442640554f;
  const float c7=0.4570457994644658f, c8=0.3731763325901154f, c9=1.445305721320277f;

  for(int idx=beg; idx<endp; idx++){
    int e = elist[idx];
    int snd = eidx[e];
    float vx = px - pos[snd*3+0] + shifts[e*3+0];
    float vy = py - pos[snd*3+1] + shifts[e*3+1];
    float vz = pz - pos[snd*3+2] + shifts[e*3+2];
    float r = sqrtf(vx*vx+vy*vy+vz*vz + 1e-12f);
    float invr = 1.f/r;
    float x=vx*invr, y=vy*invr, z=vz*invr;
    float Y[16]; sph16(x,y,z,Y);
    float rs = r*TAB_SCALE;
    int i0 = (int)rs; i0 = i0 < NPTS-2 ? i0 : NPTS-2;
    float fr = rs - (float)i0;
    const float* t0 = w_tab  + i0*64 + lane;
    const float* d0 = dw_tab + i0*64 + lane;
    float w    = t0[0] + fr*(t0[64]-t0[0]);
    float dwdr = d0[0] + fr*(d0[64]-d0[0]);
    float hk = h[(size_t)snd*64+lane];
    float wh = w*hk;
    float gw = 0.f;
    #pragma unroll
    for(int lm=0;lm<16;lm++) gw += gm[lm]*Y[lm];
    gw *= hk;
    float x2=x*x, y2=y*y, z2=z*z;
    float fz1 = 5.f*z2-1.f;
    float gxp = c1*gm[3] + c2*(y*gm[4] + z*gm[7]) + 2.f*c4*x*gm[8]
              + 6.f*c5*x*y*gm[9] + c6*y*z*gm[10] + c7*fz1*gm[13]
              + 2.f*c9*x*z*gm[14] + 3.f*c5*(x2-y2)*gm[15];
    float gyp = c1*gm[1] + c2*(x*gm[4] + z*gm[5]) - 2.f*c4*y*gm[8]
              + 3.f*c5*(x2-y2)*gm[9] + c6*x*z*gm[10] + c7*fz1*gm[11]
              - 2.f*c9*y*z*gm[14] - 6.f*c5*x*y*gm[15];
    float gzp = c1*gm[2] + c2*(y*gm[5] + x*gm[7]) + 6.f*c3*z*gm[6]
              + c6*x*y*gm[10] + 10.f*c7*y*z*gm[11] + c8*(15.f*z2-3.f)*gm[12]
              + 10.f*c7*x*z*gm[13] + c9*(x2-y2)*gm[14];
    float gx = gxp*wh*SQ4PI, gy = gyp*wh*SQ4PI, gz = gzp*wh*SQ4PI;
    float grp = gw*dwdr;
    #pragma unroll
    for(int off=32; off; off>>=1){
      gx  += __shfl_xor(gx,  off, 64);
      gy  += __shfl_xor(gy,  off, 64);
      gz  += __shfl_xor(gz,  off, 64);
      grp += __shfl_xor(grp, off, 64);
    }
    float udot = x*gx + y*gy + z*gz;
    float gvx = grp*x + (gx - udot*x)*invr;
    float gvy = grp*y + (gy - udot*y)*invr;
    float gvz = grp*z + (gz - udot*z)*invr;
    fx -= gvx; fy -= gvy; fz -= gvz;
    if(lane==0){
      atomicAdd(&forces[snd*3+0],  gvx);
      atomicAdd(&forces[snd*3+1],  gvy);
      atomicAdd(&forces[snd*3+2],  gvz);
    }
  }
  if(lane==0){
    atomicAdd(&forces[n*3+0], fx);
    atomicAdd(&forces[n*3+1], fy);
    atomicAdd(&forces[n*3+2], fz);
  }
}

// ---------------- finalize ---------------------------------------------
__global__ void fin_k(const float* __restrict__ e_acc, float* __restrict__ out, int G){
  int g = threadIdx.x;
  if(g < G){
    float e0 = e_acc[2*g], e1 = e_acc[2*g+1];
    out[g] = e0+e1;
    out[G + 2*g] = e0;
    out[G + 2*g+1] = e1;
  }
}

extern "C" void kernel_launch(void* const* d_in, const int* in_sizes, int n_in,
                              void* d_out, int out_size, void* d_ws, size_t ws_size,
                              hipStream_t stream) {
  const float* positions  = (const float*)d_in[0];
  const float* node_attrs = (const float*)d_in[1];
  const float* shifts     = (const float*)d_in[2];
  const float* W_embed    = (const float*)d_in[3];
  const float* at_en      = (const float*)d_in[4];
  const float* W_r1       = (const float*)d_in[5];
  const float* W_r2       = (const float*)d_in[6];
  const float* W_mix      = (const float*)d_in[7];
  const float* W_prod     = (const float*)d_in[8];
  const float* w_ro       = (const float*)d_in[9];
  const int*   edge_index = (const int*)d_in[10];
  const int*   batch      = (const int*)d_in[11];

  int N = in_sizes[0]/3;
  int E = in_sizes[10]/2;
  int G = (out_size - 3*N)/3;

  // l-grouped rows, each region padded to multiple of 16
  int Mp0 = (N   + 15) & ~15;
  int Mp1 = (3*N + 15) & ~15;
  int Mp2 = (5*N + 15) & ~15;
  int Mp3 = (7*N + 15) & ~15;
  int O0 = 0, O1 = Mp0, O2 = O1 + Mp1, O3 = O2 + Mp2;
  int Mp = O3 + Mp3;
  int T   = Mp  / 16;
  int tt1 = Mp0 / 16;
  int tt2 = tt1 + Mp1/16;
  int tt3 = tt2 + Mp2/16;

  float* out = (float*)d_out;
  unsigned int* AhL  = (unsigned int*)d_ws;       // [Mp][32] bf16 pairs; reused as gAH
  unsigned int* AmH  = AhL + (size_t)Mp*32;       // [Mp][32]
  unsigned int* gAmL = AmH + (size_t)Mp*32;       // [Mp][32]
  float* h      = (float*)(gAmL + (size_t)Mp*32); // N*64
  float* w_tab  = h + (size_t)N*64;               // NPTS*64
  float* dw_tab = w_tab + (size_t)NPTS*64;        // NPTS*64
  unsigned int* Wpc = (unsigned int*)(dw_tab + (size_t)NPTS*64); // 8192
  unsigned int* Wpr = Wpc + 8192;                 // 8192
  float* eacc   = (float*)(Wpr + 8192);           // 2G
  float* node_e = eacc + 2*G;                     // 2N
  int*   deg    = (int*)(node_e + 2*N);           // N
  int*   rowptr = deg + N;                        // N+1
  int*   cursor = rowptr + N + 1;                 // N
  int*   elist  = cursor + N;                     // E

  hipMemsetAsync(d_out, 0, (size_t)out_size*sizeof(float), stream);
  hipMemsetAsync(eacc, 0, (size_t)2*G*sizeof(float), stream);
  hipMemsetAsync(deg, 0, (size_t)N*sizeof(int), stream);

  embed_k<<<N, 64, 0, stream>>>(node_attrs, W_embed, at_en, batch, h, node_e, N);
  tab_k<<<NPTS, 64, 0, stream>>>(W_r1, W_r2, w_tab, dw_tab);
  pack_k<<<32, 256, 0, stream>>>(W_mix, Wpc, Wpr);
  count_k<<<(E+255)/256, 256, 0, stream>>>(positions, shifts, edge_index, deg, E);
  scan_k<<<1, 256, 0, stream>>>(deg, rowptr, cursor, N);
  scatter_k<<<(E+255)/256, 256, 0, stream>>>(positions, shifts, edge_index, cursor, elist, E);
  fwd_tab<<<(N+3)/4, 256, 0, stream>>>(positions, shifts, edge_index, h, w_tab,
                                       rowptr, elist, AhL, N, E, O0,O1,O2,O3);
  gemm_k<<<(T+3)/4, 256, 0, stream>>>(AhL, Wpc, AmH, tt1, tt2, tt3, T);
  mid_k<<<(N+3)/4, 256, 0, stream>>>(AmH, W_prod, w_ro, node_e, gAmL, N, O0,O1,O2,O3);
  gemm_k<<<(T+3)/4, 256, 0, stream>>>(gAmL, Wpr, AhL, tt1, tt2, tt3, T);  // gAH := AhL
  ered_k<<<16, 256, 0, stream>>>(node_e, batch, eacc, N, G);
  bwd_tab<<<(N+3)/4, 256, 0, stream>>>(positions, shifts, edge_index, h, w_tab, dw_tab,
                                       AhL, rowptr, elist, out + 3*G, N, E, O0,O1,O2,O3);
  fin_k<<<1, 64, 0, stream>>>(eacc, out, G);
}

// Round 14
// 163.140 us; speedup vs baseline: 2.4704x; 1.1847x over previous
//
#include <hip/hip_runtime.h>
#include <cmath>

#define RMAXF 5.0f
#define INV_AVG (1.0f/16.0f)
#define SQ4PI 3.5449077018110318f
#define NPTS 4096
#define TAB_SCALE ((float)(NPTS-1)/RMAXF)

typedef short short8 __attribute__((ext_vector_type(8)));
typedef float f32x4 __attribute__((ext_vector_type(4)));

__device__ __forceinline__ unsigned int bfr(float x){
  unsigned int u = __float_as_uint(x);
  u += 0x7fffu + ((u>>16)&1u);
  return u>>16;
}
__device__ __forceinline__ unsigned int pkbf(float a, float b){
  return bfr(a) | (bfr(b)<<16);
}
__device__ __forceinline__ float unlo(unsigned int u){ return __uint_as_float(u<<16); }
__device__ __forceinline__ float unhi(unsigned int u){ return __uint_as_float(u & 0xffff0000u); }
__device__ __forceinline__ short8 as_s8(uint4 u){ short8 r; __builtin_memcpy(&r,&u,16); return r; }

// l-grouped row index: rows[lm] = O_l + n*(2l+1) + m
__device__ __forceinline__ void node_rows(int n, int O0,int O1,int O2,int O3, int* rows){
  rows[0]=O0+n;
  int r1=O1+n*3;
  rows[1]=r1; rows[2]=r1+1; rows[3]=r1+2;
  int r2=O2+n*5;
  #pragma unroll
  for(int m=0;m<5;m++) rows[4+m]=r2+m;
  int r3=O3+n*7;
  #pragma unroll
  for(int m=0;m<7;m++) rows[9+m]=r3+m;
}

// Real sph harmonics l=0..3 (times sqrt(4pi)) of unit vector (x,y,z)
__device__ __forceinline__ void sph16(float x, float y, float z, float* Y){
  float x2=x*x, y2=y*y, z2=z*z;
  Y[0]=SQ4PI*0.28209479177387814f;
  Y[1]=SQ4PI*0.4886025119029199f*y;
  Y[2]=SQ4PI*0.4886025119029199f*z;
  Y[3]=SQ4PI*0.4886025119029199f*x;
  Y[4]=SQ4PI*1.0925484305920792f*x*y;
  Y[5]=SQ4PI*1.0925484305920792f*y*z;
  Y[6]=SQ4PI*0.31539156525252005f*(3.f*z2-1.f);
  Y[7]=SQ4PI*1.0925484305920792f*x*z;
  Y[8]=SQ4PI*0.5462742152960396f*(x2-y2);
  Y[9]=SQ4PI*0.5900435899266435f*y*(3.f*x2-y2);
  Y[10]=SQ4PI*2.890611442640554f*x*y*z;
  Y[11]=SQ4PI*0.4570457994644658f*y*(5.f*z2-1.f);
  Y[12]=SQ4PI*0.3731763325901154f*z*(5.f*z2-3.f);
  Y[13]=SQ4PI*0.4570457994644658f*x*(5.f*z2-1.f);
  Y[14]=SQ4PI*1.445305721320277f*z*(x2-y2);
  Y[15]=SQ4PI*0.5900435899266435f*x*(x2-3.f*y2);
}

// radial basis ef[8] = bess*fcut and d(ef)/dr (table builder only)
__device__ __forceinline__ void radial(float r, float* ef, float* def){
  const float PI_ = 3.14159265358979323846f;
  const float c = 0.6324555320336759f; // sqrt(2/5)
  float xr = r*(1.0f/RMAXF);
  float x2=xr*xr, x3=x2*xr, x5=x3*x2, x6=x5*xr, x7=x6*xr, x8=x7*xr;
  float fcut = 1.f - 28.f*x6 + 48.f*x7 - 21.f*x8;
  float om = 1.f - xr;
  float dfcut = -168.f*x5*om*om*(1.0f/RMAXF);
  float invr = 1.f/r;
  #pragma unroll
  for(int n=1;n<=8;n++){
    float a = (float)n*PI_*(1.0f/RMAXF);
    float ar = a*r;
    float s, co;
    sincosf(ar, &s, &co);
    float b = c*s*invr;
    ef[n-1] = b*fcut;
    def[n-1] = c*(a*co - s*invr)*invr*fcut + b*dfcut;
  }
}

// ---------------- fused prep: tab (NPTS blocks) | pack (128) | embed (N) --
__global__ __launch_bounds__(64) void prep_k(
    const float* __restrict__ W_r1, const float* __restrict__ W_r2,
    const float* __restrict__ W_mix,
    const float* __restrict__ attrs, const float* __restrict__ W_embed,
    const float* __restrict__ ae,
    float* __restrict__ w_tab, float* __restrict__ dw_tab,
    unsigned int* __restrict__ Wpc, unsigned int* __restrict__ Wpr,
    float* __restrict__ h, float* __restrict__ node_e, int N)
{
  __shared__ float s_sil[64], s_ds[64];
  int b = blockIdx.x, lane = threadIdx.x;
  if(b < NPTS){
    float r = fmaxf((float)b * (RMAXF/(float)(NPTS-1)), 1e-6f);
    float ef[8], def[8];
    radial(r, ef, def);
    float t = 0.f, dt = 0.f;
    #pragma unroll
    for(int j=0;j<8;j++){ t += ef[j]*W_r1[j*64+lane]; dt += def[j]*W_r1[j*64+lane]; }
    float sig = 1.f/(1.f+expf(-t));
    s_sil[lane] = t*sig;
    s_ds[lane]  = sig*(1.f + t*(1.f-sig))*dt;
    __syncthreads();
    float w = 0.f, dw = 0.f;
    for(int j=0;j<64;j++){
      w  += s_sil[j]*W_r2[j*64+lane];
      dw += s_ds[j] *W_r2[j*64+lane];
    }
    w_tab[b*64+lane]  = w;
    dw_tab[b*64+lane] = dw;
  } else if(b < NPTS+128){
    int i = (b-NPTS)*64 + lane;   // i < 8192
    int l = i >> 11, a = (i >> 5) & 63, p = i & 31;
    Wpc[i] = pkbf(W_mix[l*4096 + (2*p)*64 + a], W_mix[l*4096 + (2*p+1)*64 + a]);
    Wpr[i] = pkbf(W_mix[l*4096 + a*64 + 2*p], W_mix[l*4096 + a*64 + 2*p+1]);
  } else {
    int n = b - NPTS - 128;
    if(n >= N) return;
    float acc = 0.f;
    #pragma unroll
    for(int s=0;s<10;s++) acc += attrs[n*10+s]*W_embed[s*64+lane];
    h[(size_t)n*64+lane] = acc;
    if(lane==0){
      float e0 = 0.f;
      #pragma unroll
      for(int s=0;s<10;s++) e0 += attrs[n*10+s]*ae[s];
      node_e[2*n] = e0;
    }
  }
}

// ---------------- CSR build over surviving edges (r < RMAX), key = recv ---
__global__ __launch_bounds__(256) void count_k(
    const float* __restrict__ pos, const float* __restrict__ shifts,
    const int* __restrict__ eidx, int* __restrict__ deg, int E)
{
  int e = blockIdx.x*256 + threadIdx.x;
  if(e >= E) return;
  int snd = eidx[e], rcv = eidx[E+e];
  float vx = pos[rcv*3+0]-pos[snd*3+0]+shifts[e*3+0];
  float vy = pos[rcv*3+1]-pos[snd*3+1]+shifts[e*3+1];
  float vz = pos[rcv*3+2]-pos[snd*3+2]+shifts[e*3+2];
  float r2 = vx*vx+vy*vy+vz*vz + 1e-12f;
  if(r2 < RMAXF*RMAXF) atomicAdd(&deg[rcv], 1);
}

__global__ __launch_bounds__(256) void scan_k(
    const int* __restrict__ deg, int* __restrict__ rowptr,
    int* __restrict__ cursor, int N)
{
  __shared__ int part[256];
  int tid = threadIdx.x;
  int chunk = (N + 255) / 256;
  int begin = tid*chunk, end = begin+chunk < N ? begin+chunk : N;
  int s = 0;
  for(int i=begin;i<end;i++) s += deg[i];
  part[tid] = s;
  __syncthreads();
  for(int off=1; off<256; off<<=1){
    int t = (tid >= off) ? part[tid-off] : 0;
    __syncthreads();
    part[tid] += t;
    __syncthreads();
  }
  int run = part[tid] - s;   // exclusive prefix of this thread's chunk
  for(int i=begin;i<end;i++){
    rowptr[i] = run; cursor[i] = run; run += deg[i];
  }
  if(tid == 255) rowptr[N] = part[255];
}

__global__ __launch_bounds__(256) void scatter_k(
    const float* __restrict__ pos, const float* __restrict__ shifts,
    const int* __restrict__ eidx, int* __restrict__ cursor,
    int* __restrict__ elist, int E)
{
  int e = blockIdx.x*256 + threadIdx.x;
  if(e >= E) return;
  int snd = eidx[e], rcv = eidx[E+e];
  float vx = pos[rcv*3+0]-pos[snd*3+0]+shifts[e*3+0];
  float vy = pos[rcv*3+1]-pos[snd*3+1]+shifts[e*3+1];
  float vz = pos[rcv*3+2]-pos[snd*3+2]+shifts[e*3+2];
  float r2 = vx*vx+vy*vy+vz*vz + 1e-12f;
  if(r2 < RMAXF*RMAXF){
    int p = atomicAdd(&cursor[rcv], 1);
    elist[p] = e;
  }
}

// ---------------- edge forward: one wave per node, 2-edge ILP -------------
__device__ __forceinline__ void fwd_body(
    int e, const float* __restrict__ pos, const float* __restrict__ shifts,
    const int* __restrict__ eidx, const float* __restrict__ h,
    const float* __restrict__ w_tab,
    float px, float py, float pz, int lane, float* acc)
{
  int snd = eidx[e];
  float vx = px - pos[snd*3+0] + shifts[e*3+0];
  float vy = py - pos[snd*3+1] + shifts[e*3+1];
  float vz = pz - pos[snd*3+2] + shifts[e*3+2];
  float r = sqrtf(vx*vx+vy*vy+vz*vz + 1e-12f);
  float invr = 1.f/r;
  float Y[16]; sph16(vx*invr, vy*invr, vz*invr, Y);
  float rs = r*TAB_SCALE;
  int i0 = (int)rs; i0 = i0 < NPTS-2 ? i0 : NPTS-2;
  float fr = rs - (float)i0;
  const float* t0 = w_tab + i0*64 + lane;
  float w0 = t0[0], w1 = t0[64];
  float w = w0 + fr*(w1-w0);
  float wh = w * h[(size_t)snd*64+lane] * INV_AVG;
  #pragma unroll
  for(int lm=0;lm<16;lm++) acc[lm] += wh*Y[lm];
}

__global__ __launch_bounds__(256) void fwd_tab(
    const float* __restrict__ pos, const float* __restrict__ shifts,
    const int* __restrict__ eidx, const float* __restrict__ h,
    const float* __restrict__ w_tab,
    const int* __restrict__ rowptr, const int* __restrict__ elist,
    unsigned int* __restrict__ AhL, int N, int E,
    int O0,int O1,int O2,int O3)
{
  int tid = threadIdx.x, ws4 = tid >> 6, lane = tid & 63;
  int n = blockIdx.x*4 + ws4;
  if(n >= N) return;
  int beg = rowptr[n], endp = rowptr[n+1];
  float acc[16];
  #pragma unroll
  for(int lm=0;lm<16;lm++) acc[lm] = 0.f;
  float px = pos[n*3+0], py = pos[n*3+1], pz = pos[n*3+2];
  int idx = beg;
  for(; idx+1 < endp; idx += 2){
    fwd_body(elist[idx],   pos, shifts, eidx, h, w_tab, px,py,pz, lane, acc);
    fwd_body(elist[idx+1], pos, shifts, eidx, h, w_tab, px,py,pz, lane, acc);
  }
  if(idx < endp)
    fwd_body(elist[idx], pos, shifts, eidx, h, w_tab, px,py,pz, lane, acc);
  int rows[16]; node_rows(n,O0,O1,O2,O3,rows);
  #pragma unroll
  for(int lm=0;lm<16;lm++){
    float nb = __shfl_xor(acc[lm], 1, 64);
    if(!(lane&1)) AhL[(size_t)rows[lm]*32 + (lane>>1)] = pkbf(acc[lm], nb);
  }
}

// ---------------- node GEMM: C[M x 64] = A[M x 64] @ B_l[64 x 64] ---------
__global__ __launch_bounds__(256) void gemm_k(
    const unsigned int* __restrict__ Asrc,
    const unsigned int* __restrict__ Wsrc,
    unsigned int* __restrict__ Cdst,
    int t1, int t2, int t3, int T)
{
  int wv = threadIdx.x >> 6, lane = threadIdx.x & 63;
  int lrow = lane & 15, lblk = lane >> 4;
  for(int t = blockIdx.x*4 + wv; t < T; t += gridDim.x*4){
    int l = (t < t1) ? 0 : ((t < t2) ? 1 : ((t < t3) ? 2 : 3));
    const unsigned int* Wb = Wsrc + l*2048;
    int rowbase = t*16;
    const uint4* arow = (const uint4*)(Asrc + (size_t)rowbase*32);
    short8 aF0 = as_s8(arow[lrow*8 + lblk]);
    short8 aF1 = as_s8(arow[lrow*8 + 4 + lblk]);
    #pragma unroll
    for(int j=0;j<4;j++){
      int c = j*16 + lrow;
      uint4 b0u = *(const uint4*)(Wb + c*32 + lblk*4);
      uint4 b1u = *(const uint4*)(Wb + c*32 + 16 + lblk*4);
      f32x4 acc = {0.f,0.f,0.f,0.f};
      acc = __builtin_amdgcn_mfma_f32_16x16x32_bf16(aF0, as_s8(b0u), acc, 0,0,0);
      acc = __builtin_amdgcn_mfma_f32_16x16x32_bf16(aF1, as_s8(b1u), acc, 0,0,0);
      #pragma unroll
      for(int r=0;r<4;r++){
        float v = acc[r];
        float nb = __shfl_xor(v, 1, 64);
        if(!(lane&1)){
          int grow = rowbase + lblk*4 + r;
          Cdst[(size_t)grow*32 + j*8 + (lrow>>1)] = pkbf(v, nb);
        }
      }
    }
  }
}

// ---------------- node nonlinear middle: s, B, e1, gAm --------------------
__global__ __launch_bounds__(256) void mid_k(
    const unsigned int* __restrict__ AmH,
    const float* __restrict__ W_prod, const float* __restrict__ w_ro,
    float* __restrict__ node_e,
    unsigned int* __restrict__ gAmL, int N, int O0,int O1,int O2,int O3)
{
  int wv = threadIdx.x >> 6, lane = threadIdx.x & 63;
  int n = blockIdx.x*4 + wv;
  if(n >= N) return;
  int rows[16]; node_rows(n,O0,O1,O2,O3,rows);
  float am[16];
  #pragma unroll
  for(int lm=0;lm<16;lm++){
    unsigned int u = AmH[(size_t)rows[lm]*32 + (lane>>1)];
    am[lm] = (lane&1) ? unhi(u) : unlo(u);
  }
  float s_ = 0.f;
  #pragma unroll
  for(int lm=0;lm<16;lm++) s_ += am[lm]*am[lm];
  float a0_ = am[0];
  float wp0 = W_prod[lane], wp1 = W_prod[64+lane], wp2 = W_prod[128+lane];
  float wr = w_ro[lane];
  float Bv = wp0*a0_ + wp1*s_ + wp2*a0_*s_;
  float v = Bv*wr;
  #pragma unroll
  for(int off=32; off; off>>=1) v += __shfl_xor(v, off, 64);
  if(lane==0) node_e[2*n+1] = v;
  float gs = wr*(wp1 + wp2*a0_);
  #pragma unroll
  for(int lm=0;lm<16;lm++){
    float g = gs*2.f*am[lm];
    if(lm==0) g += wr*(wp0 + wp2*s_);
    float nb = __shfl_xor(g, 1, 64);
    if(!(lane&1)) gAmL[(size_t)rows[lm]*32 + (lane>>1)] = pkbf(g, nb);
  }
}

// ---------------- per-graph energy reduction (few atomics) ----------------
__global__ __launch_bounds__(256) void ered_k(
    const float* __restrict__ node_e, const int* __restrict__ batch,
    float* __restrict__ e_acc, int N, int G)
{
  __shared__ float sE[64];
  int tid = threadIdx.x;
  if(tid < 2*G) sE[tid] = 0.f;
  __syncthreads();
  for(int i = blockIdx.x*256 + tid; i < N; i += gridDim.x*256){
    int g = batch[i];
    atomicAdd(&sE[2*g],   node_e[2*i]);
    atomicAdd(&sE[2*g+1], node_e[2*i+1]);
  }
  __syncthreads();
  if(tid < 2*G){
    float v = sE[tid];
    if(v != 0.f) atomicAdd(&e_acc[tid], v);
  }
}

// ---------------- edge backward: ONE WAVE PER EDGE ------------------------
__global__ __launch_bounds__(256) void bwd_edge(
    const float* __restrict__ pos, const float* __restrict__ shifts,
    const int* __restrict__ eidx, const float* __restrict__ h,
    const float* __restrict__ w_tab, const float* __restrict__ dw_tab,
    const unsigned int* __restrict__ gAH,
    const int* __restrict__ nselp, const int* __restrict__ elist,
    float* __restrict__ forces, int E,
    int O0,int O1,int O2,int O3)
{
  int tid = threadIdx.x, wv = tid >> 6, lane = tid & 63;
  int widx = blockIdx.x*4 + wv;
  if(widx >= *nselp) return;
  int e = elist[widx];
  int snd = eidx[e], rcv = eidx[E+e];
  int rows[16]; node_rows(rcv,O0,O1,O2,O3,rows);
  float gm[16];
  #pragma unroll
  for(int lm=0;lm<16;lm++){
    unsigned int u = gAH[(size_t)rows[lm]*32 + (lane>>1)];
    gm[lm] = ((lane&1) ? unhi(u) : unlo(u)) * INV_AVG;
  }
  float vx = pos[rcv*3+0] - pos[snd*3+0] + shifts[e*3+0];
  float vy = pos[rcv*3+1] - pos[snd*3+1] + shifts[e*3+1];
  float vz = pos[rcv*3+2] - pos[snd*3+2] + shifts[e*3+2];
  float r = sqrtf(vx*vx+vy*vy+vz*vz + 1e-12f);
  float invr = 1.f/r;
  float x=vx*invr, y=vy*invr, z=vz*invr;
  float Y[16]; sph16(x,y,z,Y);
  float rs = r*TAB_SCALE;
  int i0 = (int)rs; i0 = i0 < NPTS-2 ? i0 : NPTS-2;
  float fr = rs - (float)i0;
  const float* t0 = w_tab  + i0*64 + lane;
  const float* d0 = dw_tab + i0*64 + lane;
  float w    = t0[0] + fr*(t0[64]-t0[0]);
  float dwdr = d0[0] + fr*(d0[64]-d0[0]);
  float hk = h[(size_t)snd*64+lane];
  float wh = w*hk;
  float gw = 0.f;
  #pragma unroll
  for(int lm=0;lm<16;lm++) gw += gm[lm]*Y[lm];
  gw *= hk;
  const float c1=0.4886025119029199f, c2=1.0925484305920792f, c3=0.31539156525252005f;
  const float c4=0.5462742152960396f, c5=0.5900435899266435f, c6=2.890611442640554f;
  const float c7=0.4570457994644658f, c8=0.3731763325901154f, c9=1.445305721320277f;
  float x2=x*x, y2=y*y, z2=z*z;
  float fz1 = 5.f*z2-1.f;
  float gxp = c1*gm[3] + c2*(y*gm[4] + z*gm[7]) + 2.f*c4*x*gm[8]
            + 6.f*c5*x*y*gm[9] + c6*y*z*gm[10] + c7*fz1*gm[13]
            + 2.f*c9*x*z*gm[14] + 3.f*c5*(x2-y2)*gm[15];
  float gyp = c1*gm[1] + c2*(x*gm[4] + z*gm[5]) - 2.f*c4*y*gm[8]
            + 3.f*c5*(x2-y2)*gm[9] + c6*x*z*gm[10] + c7*fz1*gm[11]
            - 2.f*c9*y*z*gm[14] - 6.f*c5*x*y*gm[15];
  float gzp = c1*gm[2] + c2*(y*gm[5] + x*gm[7]) + 6.f*c3*z*gm[6]
            + c6*x*y*gm[10] + 10.f*c7*y*z*gm[11] + c8*(15.f*z2-3.f)*gm[12]
            + 10.f*c7*x*z*gm[13] + c9*(x2-y2)*gm[14];
  float gx = gxp*wh*SQ4PI, gy = gyp*wh*SQ4PI, gz = gzp*wh*SQ4PI;
  float grp = gw*dwdr;
  #pragma unroll
  for(int off=32; off; off>>=1){
    gx  += __shfl_xor(gx,  off, 64);
    gy  += __shfl_xor(gy,  off, 64);
    gz  += __shfl_xor(gz,  off, 64);
    grp += __shfl_xor(grp, off, 64);
  }
  float udot = x*gx + y*gy + z*gz;
  float gvx = grp*x + (gx - udot*x)*invr;
  float gvy = grp*y + (gy - udot*y)*invr;
  float gvz = grp*z + (gz - udot*z)*invr;
  if(lane==0){
    atomicAdd(&forces[snd*3+0],  gvx);
    atomicAdd(&forces[snd*3+1],  gvy);
    atomicAdd(&forces[snd*3+2],  gvz);
    atomicAdd(&forces[rcv*3+0], -gvx);
    atomicAdd(&forces[rcv*3+1], -gvy);
    atomicAdd(&forces[rcv*3+2], -gvz);
  }
}

// ---------------- finalize ---------------------------------------------
__global__ void fin_k(const float* __restrict__ e_acc, float* __restrict__ out, int G){
  int g = threadIdx.x;
  if(g < G){
    float e0 = e_acc[2*g], e1 = e_acc[2*g+1];
    out[g] = e0+e1;
    out[G + 2*g] = e0;
    out[G + 2*g+1] = e1;
  }
}

extern "C" void kernel_launch(void* const* d_in, const int* in_sizes, int n_in,
                              void* d_out, int out_size, void* d_ws, size_t ws_size,
                              hipStream_t stream) {
  const float* positions  = (const float*)d_in[0];
  const float* node_attrs = (const float*)d_in[1];
  const float* shifts     = (const float*)d_in[2];
  const float* W_embed    = (const float*)d_in[3];
  const float* at_en      = (const float*)d_in[4];
  const float* W_r1       = (const float*)d_in[5];
  const float* W_r2       = (const float*)d_in[6];
  const float* W_mix      = (const float*)d_in[7];
  const float* W_prod     = (const float*)d_in[8];
  const float* w_ro       = (const float*)d_in[9];
  const int*   edge_index = (const int*)d_in[10];
  const int*   batch      = (const int*)d_in[11];

  int N = in_sizes[0]/3;
  int E = in_sizes[10]/2;
  int G = (out_size - 3*N)/3;

  // l-grouped rows, each region padded to multiple of 16
  int Mp0 = (N   + 15) & ~15;
  int Mp1 = (3*N + 15) & ~15;
  int Mp2 = (5*N + 15) & ~15;
  int Mp3 = (7*N + 15) & ~15;
  int O0 = 0, O1 = Mp0, O2 = O1 + Mp1, O3 = O2 + Mp2;
  int Mp = O3 + Mp3;
  int T   = Mp  / 16;
  int tt1 = Mp0 / 16;
  int tt2 = tt1 + Mp1/16;
  int tt3 = tt2 + Mp2/16;

  float* out = (float*)d_out;
  unsigned int* AhL  = (unsigned int*)d_ws;       // [Mp][32] bf16 pairs; reused as gAH
  unsigned int* AmH  = AhL + (size_t)Mp*32;       // [Mp][32]
  unsigned int* gAmL = AmH + (size_t)Mp*32;       // [Mp][32]
  float* h      = (float*)(gAmL + (size_t)Mp*32); // N*64
  float* w_tab  = h + (size_t)N*64;               // NPTS*64
  float* dw_tab = w_tab + (size_t)NPTS*64;        // NPTS*64
  unsigned int* Wpc = (unsigned int*)(dw_tab + (size_t)NPTS*64); // 8192
  unsigned int* Wpr = Wpc + 8192;                 // 8192
  float* eacc   = (float*)(Wpr + 8192);           // 2G
  float* node_e = eacc + 2*G;                     // 2N
  int*   deg    = (int*)(node_e + 2*N);           // N
  int*   rowptr = deg + N;                        // N+1  (rowptr[N] = nsel)
  int*   cursor = rowptr + N + 1;                 // N
  int*   elist  = cursor + N;                     // E

  hipMemsetAsync(d_out, 0, (size_t)out_size*sizeof(float), stream);
  hipMemsetAsync(eacc, 0, (size_t)2*G*sizeof(float), stream);
  hipMemsetAsync(deg, 0, (size_t)N*sizeof(int), stream);

  prep_k<<<NPTS + 128 + N, 64, 0, stream>>>(W_r1, W_r2, W_mix, node_attrs, W_embed,
                                            at_en, w_tab, dw_tab, Wpc, Wpr, h, node_e, N);
  count_k<<<(E+255)/256, 256, 0, stream>>>(positions, shifts, edge_index, deg, E);
  scan_k<<<1, 256, 0, stream>>>(deg, rowptr, cursor, N);
  scatter_k<<<(E+255)/256, 256, 0, stream>>>(positions, shifts, edge_index, cursor, elist, E);
  fwd_tab<<<(N+3)/4, 256, 0, stream>>>(positions, shifts, edge_index, h, w_tab,
                                       rowptr, elist, AhL, N, E, O0,O1,O2,O3);
  gemm_k<<<(T+3)/4, 256, 0, stream>>>(AhL, Wpc, AmH, tt1, tt2, tt3, T);
  mid_k<<<(N+3)/4, 256, 0, stream>>>(AmH, W_prod, w_ro, node_e, gAmL, N, O0,O1,O2,O3);
  gemm_k<<<(T+3)/4, 256, 0, stream>>>(gAmL, Wpr, AhL, tt1, tt2, tt3, T);  // gAH := AhL
  ered_k<<<16, 256, 0, stream>>>(node_e, batch, eacc, N, G);
  bwd_edge<<<(E+3)/4, 256, 0, stream>>>(positions, shifts, edge_index, h, w_tab, dw_tab,
                                        AhL, rowptr + N, elist, out + 3*G, E, O0,O1,O2,O3);
  fin_k<<<1, 64, 0, stream>>>(eacc, out, G);
}

// Round 15
// 141.115 us; speedup vs baseline: 2.8560x; 1.1561x over previous
//
#include <hip/hip_runtime.h>
#include <cmath>

#define RMAXF 5.0f
#define INV_AVG (1.0f/16.0f)
#define SQ4PI 3.5449077018110318f
#define NPTS 4096
#define TAB_SCALE ((float)(NPTS-1)/RMAXF)

typedef short short8 __attribute__((ext_vector_type(8)));
typedef float f32x4 __attribute__((ext_vector_type(4)));

__device__ __forceinline__ unsigned int bfr(float x){
  unsigned int u = __float_as_uint(x);
  u += 0x7fffu + ((u>>16)&1u);
  return u>>16;
}
__device__ __forceinline__ unsigned int pkbf(float a, float b){
  return bfr(a) | (bfr(b)<<16);
}
__device__ __forceinline__ float unlo(unsigned int u){ return __uint_as_float(u<<16); }
__device__ __forceinline__ float unhi(unsigned int u){ return __uint_as_float(u & 0xffff0000u); }
__device__ __forceinline__ short8 as_s8(uint4 u){ short8 r; __builtin_memcpy(&r,&u,16); return r; }

// l-grouped row index: rows[lm] = O_l + n*(2l+1) + m
__device__ __forceinline__ void node_rows(int n, int O0,int O1,int O2,int O3, int* rows){
  rows[0]=O0+n;
  int r1=O1+n*3;
  rows[1]=r1; rows[2]=r1+1; rows[3]=r1+2;
  int r2=O2+n*5;
  #pragma unroll
  for(int m=0;m<5;m++) rows[4+m]=r2+m;
  int r3=O3+n*7;
  #pragma unroll
  for(int m=0;m<7;m++) rows[9+m]=r3+m;
}

// Real sph harmonics l=0..3 (times sqrt(4pi)) of unit vector (x,y,z)
__device__ __forceinline__ void sph16(float x, float y, float z, float* Y){
  float x2=x*x, y2=y*y, z2=z*z;
  Y[0]=SQ4PI*0.28209479177387814f;
  Y[1]=SQ4PI*0.4886025119029199f*y;
  Y[2]=SQ4PI*0.4886025119029199f*z;
  Y[3]=SQ4PI*0.4886025119029199f*x;
  Y[4]=SQ4PI*1.0925484305920792f*x*y;
  Y[5]=SQ4PI*1.0925484305920792f*y*z;
  Y[6]=SQ4PI*0.31539156525252005f*(3.f*z2-1.f);
  Y[7]=SQ4PI*1.0925484305920792f*x*z;
  Y[8]=SQ4PI*0.5462742152960396f*(x2-y2);
  Y[9]=SQ4PI*0.5900435899266435f*y*(3.f*x2-y2);
  Y[10]=SQ4PI*2.890611442640554f*x*y*z;
  Y[11]=SQ4PI*0.4570457994644658f*y*(5.f*z2-1.f);
  Y[12]=SQ4PI*0.3731763325901154f*z*(5.f*z2-3.f);
  Y[13]=SQ4PI*0.4570457994644658f*x*(5.f*z2-1.f);
  Y[14]=SQ4PI*1.445305721320277f*z*(x2-y2);
  Y[15]=SQ4PI*0.5900435899266435f*x*(x2-3.f*y2);
}

// radial basis ef[8] = bess*fcut and d(ef)/dr (table builder only)
__device__ __forceinline__ void radial(float r, float* ef, float* def){
  const float PI_ = 3.14159265358979323846f;
  const float c = 0.6324555320336759f; // sqrt(2/5)
  float xr = r*(1.0f/RMAXF);
  float x2=xr*xr, x3=x2*xr, x5=x3*x2, x6=x5*xr, x7=x6*xr, x8=x7*xr;
  float fcut = 1.f - 28.f*x6 + 48.f*x7 - 21.f*x8;
  float om = 1.f - xr;
  float dfcut = -168.f*x5*om*om*(1.0f/RMAXF);
  float invr = 1.f/r;
  #pragma unroll
  for(int n=1;n<=8;n++){
    float a = (float)n*PI_*(1.0f/RMAXF);
    float ar = a*r;
    float s, co;
    sincosf(ar, &s, &co);
    float b = c*s*invr;
    ef[n-1] = b*fcut;
    def[n-1] = c*(a*co - s*invr)*invr*fcut + b*dfcut;
  }
}

// -------- fused prep: tab | pack | embed | zero-forces | count -----------
__global__ __launch_bounds__(64) void prep_k(
    const float* __restrict__ W_r1, const float* __restrict__ W_r2,
    const float* __restrict__ W_mix,
    const float* __restrict__ attrs, const float* __restrict__ W_embed,
    const float* __restrict__ ae,
    const float* __restrict__ pos, const float* __restrict__ shifts,
    const int* __restrict__ eidx,
    float* __restrict__ w_tab, float* __restrict__ dw_tab,
    unsigned int* __restrict__ Wpc, unsigned int* __restrict__ Wpr,
    float* __restrict__ h, float* __restrict__ node_e,
    float* __restrict__ forces, int* __restrict__ deg,
    int N, int E, int FZ)
{
  __shared__ float s_sil[64], s_ds[64];
  int b = blockIdx.x, lane = threadIdx.x;
  if(b < NPTS){
    float r = fmaxf((float)b * (RMAXF/(float)(NPTS-1)), 1e-6f);
    float ef[8], def[8];
    radial(r, ef, def);
    float t = 0.f, dt = 0.f;
    #pragma unroll
    for(int j=0;j<8;j++){ t += ef[j]*W_r1[j*64+lane]; dt += def[j]*W_r1[j*64+lane]; }
    float sig = 1.f/(1.f+expf(-t));
    s_sil[lane] = t*sig;
    s_ds[lane]  = sig*(1.f + t*(1.f-sig))*dt;
    __syncthreads();
    float w = 0.f, dw = 0.f;
    for(int j=0;j<64;j++){
      w  += s_sil[j]*W_r2[j*64+lane];
      dw += s_ds[j] *W_r2[j*64+lane];
    }
    w_tab[b*64+lane]  = w;
    dw_tab[b*64+lane] = dw;
  } else if(b < NPTS+128){
    int i = (b-NPTS)*64 + lane;   // i < 8192
    int l = i >> 11, a = (i >> 5) & 63, p = i & 31;
    Wpc[i] = pkbf(W_mix[l*4096 + (2*p)*64 + a], W_mix[l*4096 + (2*p+1)*64 + a]);
    Wpr[i] = pkbf(W_mix[l*4096 + a*64 + 2*p], W_mix[l*4096 + a*64 + 2*p+1]);
  } else if(b < NPTS+128+N){
    int n = b - NPTS - 128;
    float acc = 0.f;
    #pragma unroll
    for(int s=0;s<10;s++) acc += attrs[n*10+s]*W_embed[s*64+lane];
    h[(size_t)n*64+lane] = acc;
    if(lane==0){
      float e0 = 0.f;
      #pragma unroll
      for(int s=0;s<10;s++) e0 += attrs[n*10+s]*ae[s];
      node_e[2*n] = e0;
    }
  } else if(b < NPTS+128+N+FZ){
    int i = (b - NPTS - 128 - N)*64 + lane;
    if(i < 3*N) forces[i] = 0.f;
  } else {
    int e = (b - NPTS - 128 - N - FZ)*64 + lane;
    if(e < E){
      int snd = eidx[e], rcv = eidx[E+e];
      float vx = pos[rcv*3+0]-pos[snd*3+0]+shifts[e*3+0];
      float vy = pos[rcv*3+1]-pos[snd*3+1]+shifts[e*3+1];
      float vz = pos[rcv*3+2]-pos[snd*3+2]+shifts[e*3+2];
      float r2 = vx*vx+vy*vy+vz*vz + 1e-12f;
      if(r2 < RMAXF*RMAXF) atomicAdd(&deg[rcv], 1);
    }
  }
}

// ---------------- prefix scan over deg (1 block, 1024 threads) ------------
__global__ __launch_bounds__(1024) void scan_k(
    const int* __restrict__ deg, int* __restrict__ rowptr,
    int* __restrict__ cursor, int N)
{
  __shared__ int part[1024];
  int tid = threadIdx.x;
  int chunk = (N + 1023) / 1024;
  int begin = tid*chunk, end = begin+chunk < N ? begin+chunk : N;
  int s = 0;
  for(int i=begin;i<end;i++) s += deg[i];
  part[tid] = s;
  __syncthreads();
  for(int off=1; off<1024; off<<=1){
    int t = (tid >= off) ? part[tid-off] : 0;
    __syncthreads();
    part[tid] += t;
    __syncthreads();
  }
  int run = part[tid] - s;   // exclusive prefix of this thread's chunk
  for(int i=begin;i<end;i++){
    rowptr[i] = run; cursor[i] = run; run += deg[i];
  }
  if(tid == 1023) rowptr[N] = part[1023];
}

__global__ __launch_bounds__(256) void scatter_k(
    const float* __restrict__ pos, const float* __restrict__ shifts,
    const int* __restrict__ eidx, int* __restrict__ cursor,
    int* __restrict__ elist, int E)
{
  int e = blockIdx.x*256 + threadIdx.x;
  if(e >= E) return;
  int snd = eidx[e], rcv = eidx[E+e];
  float vx = pos[rcv*3+0]-pos[snd*3+0]+shifts[e*3+0];
  float vy = pos[rcv*3+1]-pos[snd*3+1]+shifts[e*3+1];
  float vz = pos[rcv*3+2]-pos[snd*3+2]+shifts[e*3+2];
  float r2 = vx*vx+vy*vy+vz*vz + 1e-12f;
  if(r2 < RMAXF*RMAXF){
    int p = atomicAdd(&cursor[rcv], 1);
    elist[p] = e;
  }
}

// ---------------- edge forward: TWO waves per node, LDS combine -----------
__device__ __forceinline__ void fwd_body(
    int e, const float* __restrict__ pos, const float* __restrict__ shifts,
    const int* __restrict__ eidx, const float* __restrict__ h,
    const float* __restrict__ w_tab,
    float px, float py, float pz, int lane, float* acc)
{
  int snd = eidx[e];
  float vx = px - pos[snd*3+0] + shifts[e*3+0];
  float vy = py - pos[snd*3+1] + shifts[e*3+1];
  float vz = pz - pos[snd*3+2] + shifts[e*3+2];
  float r = sqrtf(vx*vx+vy*vy+vz*vz + 1e-12f);
  float invr = 1.f/r;
  float Y[16]; sph16(vx*invr, vy*invr, vz*invr, Y);
  float rs = r*TAB_SCALE;
  int i0 = (int)rs; i0 = i0 < NPTS-2 ? i0 : NPTS-2;
  float fr = rs - (float)i0;
  const float* t0 = w_tab + i0*64 + lane;
  float w0 = t0[0], w1 = t0[64];
  float w = w0 + fr*(w1-w0);
  float wh = w * h[(size_t)snd*64+lane] * INV_AVG;
  #pragma unroll
  for(int lm=0;lm<16;lm++) acc[lm] += wh*Y[lm];
}

__global__ __launch_bounds__(256) void fwd_tab(
    const float* __restrict__ pos, const float* __restrict__ shifts,
    const int* __restrict__ eidx, const float* __restrict__ h,
    const float* __restrict__ w_tab,
    const int* __restrict__ rowptr, const int* __restrict__ elist,
    unsigned int* __restrict__ AhL, int N, int E,
    int O0,int O1,int O2,int O3)
{
  __shared__ float sBuf[2][16][64];
  int tid = threadIdx.x, wv = tid >> 6, lane = tid & 63;
  int slot = wv >> 1, p = wv & 1;
  int n = blockIdx.x*2 + slot;
  float acc[16];
  #pragma unroll
  for(int lm=0;lm<16;lm++) acc[lm] = 0.f;
  if(n < N){
    int beg = rowptr[n], endp = rowptr[n+1];
    float px = pos[n*3+0], py = pos[n*3+1], pz = pos[n*3+2];
    for(int idx = beg + p; idx < endp; idx += 2)
      fwd_body(elist[idx], pos, shifts, eidx, h, w_tab, px,py,pz, lane, acc);
  }
  if(n < N && p == 0){
    #pragma unroll
    for(int lm=0;lm<16;lm++) sBuf[slot][lm][lane] = acc[lm];
  }
  __syncthreads();
  if(n < N && p == 1){
    int rows[16]; node_rows(n,O0,O1,O2,O3,rows);
    #pragma unroll
    for(int lm=0;lm<16;lm++){
      float v = acc[lm] + sBuf[slot][lm][lane];
      float nb = __shfl_xor(v, 1, 64);
      if(!(lane&1)) AhL[(size_t)rows[lm]*32 + (lane>>1)] = pkbf(v, nb);
    }
  }
}

// ---------------- node GEMM (+ optional fused energy reduction) -----------
__global__ __launch_bounds__(256) void gemm_k(
    const unsigned int* __restrict__ Asrc,
    const unsigned int* __restrict__ Wsrc,
    unsigned int* __restrict__ Cdst,
    int t1, int t2, int t3, int T, int G1,
    const float* __restrict__ node_e, const int* __restrict__ batch,
    float* __restrict__ e_acc, int N, int G)
{
  if((int)blockIdx.x >= G1){
    // fused ered: blocks [G1, gridDim)
    __shared__ float sE[64];
    int tid = threadIdx.x;
    int bid = blockIdx.x - G1, nb = gridDim.x - G1;
    if(tid < 2*G) sE[tid] = 0.f;
    __syncthreads();
    for(int i = bid*256 + tid; i < N; i += nb*256){
      int g = batch[i];
      atomicAdd(&sE[2*g],   node_e[2*i]);
      atomicAdd(&sE[2*g+1], node_e[2*i+1]);
    }
    __syncthreads();
    if(tid < 2*G){
      float v = sE[tid];
      if(v != 0.f) atomicAdd(&e_acc[tid], v);
    }
    return;
  }
  int wv = threadIdx.x >> 6, lane = threadIdx.x & 63;
  int lrow = lane & 15, lblk = lane >> 4;
  for(int t = blockIdx.x*4 + wv; t < T; t += G1*4){
    int l = (t < t1) ? 0 : ((t < t2) ? 1 : ((t < t3) ? 2 : 3));
    const unsigned int* Wb = Wsrc + l*2048;
    int rowbase = t*16;
    const uint4* arow = (const uint4*)(Asrc + (size_t)rowbase*32);
    short8 aF0 = as_s8(arow[lrow*8 + lblk]);
    short8 aF1 = as_s8(arow[lrow*8 + 4 + lblk]);
    #pragma unroll
    for(int j=0;j<4;j++){
      int c = j*16 + lrow;
      uint4 b0u = *(const uint4*)(Wb + c*32 + lblk*4);
      uint4 b1u = *(const uint4*)(Wb + c*32 + 16 + lblk*4);
      f32x4 acc = {0.f,0.f,0.f,0.f};
      acc = __builtin_amdgcn_mfma_f32_16x16x32_bf16(aF0, as_s8(b0u), acc, 0,0,0);
      acc = __builtin_amdgcn_mfma_f32_16x16x32_bf16(aF1, as_s8(b1u), acc, 0,0,0);
      #pragma unroll
      for(int r=0;r<4;r++){
        float v = acc[r];
        float nb = __shfl_xor(v, 1, 64);
        if(!(lane&1)){
          int grow = rowbase + lblk*4 + r;
          Cdst[(size_t)grow*32 + j*8 + (lrow>>1)] = pkbf(v, nb);
        }
      }
    }
  }
}

// ---------------- node nonlinear middle: s, B, e1, gAm --------------------
__global__ __launch_bounds__(256) void mid_k(
    const unsigned int* __restrict__ AmH,
    const float* __restrict__ W_prod, const float* __restrict__ w_ro,
    float* __restrict__ node_e,
    unsigned int* __restrict__ gAmL, int N, int O0,int O1,int O2,int O3)
{
  int wv = threadIdx.x >> 6, lane = threadIdx.x & 63;
  int n = blockIdx.x*4 + wv;
  if(n >= N) return;
  int rows[16]; node_rows(n,O0,O1,O2,O3,rows);
  float am[16];
  #pragma unroll
  for(int lm=0;lm<16;lm++){
    unsigned int u = AmH[(size_t)rows[lm]*32 + (lane>>1)];
    am[lm] = (lane&1) ? unhi(u) : unlo(u);
  }
  float s_ = 0.f;
  #pragma unroll
  for(int lm=0;lm<16;lm++) s_ += am[lm]*am[lm];
  float a0_ = am[0];
  float wp0 = W_prod[lane], wp1 = W_prod[64+lane], wp2 = W_prod[128+lane];
  float wr = w_ro[lane];
  float Bv = wp0*a0_ + wp1*s_ + wp2*a0_*s_;
  float v = Bv*wr;
  #pragma unroll
  for(int off=32; off; off>>=1) v += __shfl_xor(v, off, 64);
  if(lane==0) node_e[2*n+1] = v;
  float gs = wr*(wp1 + wp2*a0_);
  #pragma unroll
  for(int lm=0;lm<16;lm++){
    float g = gs*2.f*am[lm];
    if(lm==0) g += wr*(wp0 + wp2*s_);
    float nb = __shfl_xor(g, 1, 64);
    if(!(lane&1)) gAmL[(size_t)rows[lm]*32 + (lane>>1)] = pkbf(g, nb);
  }
}

// ---------------- edge backward: one wave per edge (+ fused fin) ----------
__global__ __launch_bounds__(256) void bwd_edge(
    const float* __restrict__ pos, const float* __restrict__ shifts,
    const int* __restrict__ eidx, const float* __restrict__ h,
    const float* __restrict__ w_tab, const float* __restrict__ dw_tab,
    const unsigned int* __restrict__ gAH,
    const int* __restrict__ nselp, const int* __restrict__ elist,
    float* __restrict__ forces, int E,
    int O0,int O1,int O2,int O3,
    const float* __restrict__ e_acc, float* __restrict__ out, int G)
{
  int tid = threadIdx.x, wv = tid >> 6, lane = tid & 63;
  if(blockIdx.x == gridDim.x-1){
    // fused finalize (e_acc complete from previous launch)
    if(tid < G){
      float e0 = e_acc[2*tid], e1 = e_acc[2*tid+1];
      out[tid] = e0+e1;
      out[G + 2*tid] = e0;
      out[G + 2*tid+1] = e1;
    }
    return;
  }
  int widx = blockIdx.x*4 + wv;
  if(widx >= *nselp) return;
  int e = elist[widx];
  int snd = eidx[e], rcv = eidx[E+e];
  int rows[16]; node_rows(rcv,O0,O1,O2,O3,rows);
  float gm[16];
  #pragma unroll
  for(int lm=0;lm<16;lm++){
    unsigned int u = gAH[(size_t)rows[lm]*32 + (lane>>1)];
    gm[lm] = ((lane&1) ? unhi(u) : unlo(u)) * INV_AVG;
  }
  float vx = pos[rcv*3+0] - pos[snd*3+0] + shifts[e*3+0];
  float vy = pos[rcv*3+1] - pos[snd*3+1] + shifts[e*3+1];
  float vz = pos[rcv*3+2] - pos[snd*3+2] + shifts[e*3+2];
  float r = sqrtf(vx*vx+vy*vy+vz*vz + 1e-12f);
  float invr = 1.f/r;
  float x=vx*invr, y=vy*invr, z=vz*invr;
  float Y[16]; sph16(x,y,z,Y);
  float rs = r*TAB_SCALE;
  int i0 = (int)rs; i0 = i0 < NPTS-2 ? i0 : NPTS-2;
  float fr = rs - (float)i0;
  const float* t0 = w_tab  + i0*64 + lane;
  const float* d0 = dw_tab + i0*64 + lane;
  float w    = t0[0] + fr*(t0[64]-t0[0]);
  float dwdr = d0[0] + fr*(d0[64]-d0[0]);
  float hk = h[(size_t)snd*64+lane];
  float wh = w*hk;
  float gw = 0.f;
  #pragma unroll
  for(int lm=0;lm<16;lm++) gw += gm[lm]*Y[lm];
  gw *= hk;
  const float c1=0.4886025119029199f, c2=1.0925484305920792f, c3=0.31539156525252005f;
  const float c4=0.5462742152960396f, c5=0.5900435899266435f, c6=2.890611442640554f;
  const float c7=0.4570457994644658f, c8=0.3731763325901154f, c9=1.445305721320277f;
  float x2=x*x, y2=y*y, z2=z*z;
  float fz1 = 5.f*z2-1.f;
  float gxp = c1*gm[3] + c2*(y*gm[4] + z*gm[7]) + 2.f*c4*x*gm[8]
            + 6.f*c5*x*y*gm[9] + c6*y*z*gm[10] + c7*fz1*gm[13]
            + 2.f*c9*x*z*gm[14] + 3.f*c5*(x2-y2)*gm[15];
  float gyp = c1*gm[1] + c2*(x*gm[4] + z*gm[5]) - 2.f*c4*y*gm[8]
            + 3.f*c5*(x2-y2)*gm[9] + c6*x*z*gm[10] + c7*fz1*gm[11]
            - 2.f*c9*y*z*gm[14] - 6.f*c5*x*y*gm[15];
  float gzp = c1*gm[2] + c2*(y*gm[5] + x*gm[7]) + 6.f*c3*z*gm[6]
            + c6*x*y*gm[10] + 10.f*c7*y*z*gm[11] + c8*(15.f*z2-3.f)*gm[12]
            + 10.f*c7*x*z*gm[13] + c9*(x2-y2)*gm[14];
  float gx = gxp*wh*SQ4PI, gy = gyp*wh*SQ4PI, gz = gzp*wh*SQ4PI;
  float grp = gw*dwdr;
  #pragma unroll
  for(int off=32; off; off>>=1){
    gx  += __shfl_xor(gx,  off, 64);
    gy  += __shfl_xor(gy,  off, 64);
    gz  += __shfl_xor(gz,  off, 64);
    grp += __shfl_xor(grp, off, 64);
  }
  float udot = x*gx + y*gy + z*gz;
  float gvx = grp*x + (gx - udot*x)*invr;
  float gvy = grp*y + (gy - udot*y)*invr;
  float gvz = grp*z + (gz - udot*z)*invr;
  if(lane==0){
    atomicAdd(&forces[snd*3+0],  gvx);
    atomicAdd(&forces[snd*3+1],  gvy);
    atomicAdd(&forces[snd*3+2],  gvz);
    atomicAdd(&forces[rcv*3+0], -gvx);
    atomicAdd(&forces[rcv*3+1], -gvy);
    atomicAdd(&forces[rcv*3+2], -gvz);
  }
}

extern "C" void kernel_launch(void* const* d_in, const int* in_sizes, int n_in,
                              void* d_out, int out_size, void* d_ws, size_t ws_size,
                              hipStream_t stream) {
  const float* positions  = (const float*)d_in[0];
  const float* node_attrs = (const float*)d_in[1];
  const float* shifts     = (const float*)d_in[2];
  const float* W_embed    = (const float*)d_in[3];
  const float* at_en      = (const float*)d_in[4];
  const float* W_r1       = (const float*)d_in[5];
  const float* W_r2       = (const float*)d_in[6];
  const float* W_mix      = (const float*)d_in[7];
  const float* W_prod     = (const float*)d_in[8];
  const float* w_ro       = (const float*)d_in[9];
  const int*   edge_index = (const int*)d_in[10];
  const int*   batch      = (const int*)d_in[11];

  int N = in_sizes[0]/3;
  int E = in_sizes[10]/2;
  int G = (out_size - 3*N)/3;

  // l-grouped rows, each region padded to multiple of 16
  int Mp0 = (N   + 15) & ~15;
  int Mp1 = (3*N + 15) & ~15;
  int Mp2 = (5*N + 15) & ~15;
  int Mp3 = (7*N + 15) & ~15;
  int O0 = 0, O1 = Mp0, O2 = O1 + Mp1, O3 = O2 + Mp2;
  int Mp = O3 + Mp3;
  int T   = Mp  / 16;
  int tt1 = Mp0 / 16;
  int tt2 = tt1 + Mp1/16;
  int tt3 = tt2 + Mp2/16;
  int G1  = (T+3)/4;

  float* out = (float*)d_out;
  unsigned int* AhL  = (unsigned int*)d_ws;       // [Mp][32] bf16 pairs; reused as gAH
  unsigned int* AmH  = AhL + (size_t)Mp*32;       // [Mp][32]
  unsigned int* gAmL = AmH + (size_t)Mp*32;       // [Mp][32]
  float* h      = (float*)(gAmL + (size_t)Mp*32); // N*64
  float* w_tab  = h + (size_t)N*64;               // NPTS*64
  float* dw_tab = w_tab + (size_t)NPTS*64;        // NPTS*64
  unsigned int* Wpc = (unsigned int*)(dw_tab + (size_t)NPTS*64); // 8192
  unsigned int* Wpr = Wpc + 8192;                 // 8192
  float* eacc   = (float*)(Wpr + 8192);           // 2G   (zeroed)
  int*   deg    = (int*)(eacc + 2*G);             // N    (zeroed, contiguous w/ eacc)
  float* node_e = (float*)(deg + N);              // 2N
  int*   rowptr = (int*)(node_e + 2*N);           // N+1  (rowptr[N] = nsel)
  int*   cursor = rowptr + N + 1;                 // N
  int*   elist  = cursor + N;                     // E

  int FZ = (3*N + 63)/64;
  int CB = (E + 63)/64;

  hipMemsetAsync(eacc, 0, (size_t)(2*G + N)*sizeof(int), stream);  // eacc + deg

  prep_k<<<NPTS + 128 + N + FZ + CB, 64, 0, stream>>>(
      W_r1, W_r2, W_mix, node_attrs, W_embed, at_en,
      positions, shifts, edge_index,
      w_tab, dw_tab, Wpc, Wpr, h, node_e, out + 3*G, deg, N, E, FZ);
  scan_k<<<1, 1024, 0, stream>>>(deg, rowptr, cursor, N);
  scatter_k<<<(E+255)/256, 256, 0, stream>>>(positions, shifts, edge_index, cursor, elist, E);
  fwd_tab<<<(N+1)/2, 256, 0, stream>>>(positions, shifts, edge_index, h, w_tab,
                                       rowptr, elist, AhL, N, E, O0,O1,O2,O3);
  gemm_k<<<G1, 256, 0, stream>>>(AhL, Wpc, AmH, tt1, tt2, tt3, T, G1,
                                 nullptr, nullptr, nullptr, 0, 0);
  mid_k<<<(N+3)/4, 256, 0, stream>>>(AmH, W_prod, w_ro, node_e, gAmL, N, O0,O1,O2,O3);
  gemm_k<<<G1 + 16, 256, 0, stream>>>(gAmL, Wpr, AhL, tt1, tt2, tt3, T, G1,
                                      node_e, batch, eacc, N, G);
  bwd_edge<<<(E+3)/4 + 1, 256, 0, stream>>>(positions, shifts, edge_index, h, w_tab, dw_tab,
                                            AhL, rowptr + N, elist, out + 3*G, E,
                                            O0,O1,O2,O3, eacc, out, G);
}

// Round 16
// 140.238 us; speedup vs baseline: 2.8738x; 1.0063x over previous
//
#include <hip/hip_runtime.h>
#include <cmath>

#define RMAXF 5.0f
#define INV_AVG (1.0f/16.0f)
#define SQ4PI 3.5449077018110318f
#define NPTS 4096
#define TAB_SCALE ((float)(NPTS-1)/RMAXF)

typedef short short8 __attribute__((ext_vector_type(8)));
typedef float f32x4 __attribute__((ext_vector_type(4)));

__device__ __forceinline__ unsigned int bfr(float x){
  unsigned int u = __float_as_uint(x);
  u += 0x7fffu + ((u>>16)&1u);
  return u>>16;
}
__device__ __forceinline__ unsigned int pkbf(float a, float b){
  return bfr(a) | (bfr(b)<<16);
}
__device__ __forceinline__ float unlo(unsigned int u){ return __uint_as_float(u<<16); }
__device__ __forceinline__ float unhi(unsigned int u){ return __uint_as_float(u & 0xffff0000u); }
__device__ __forceinline__ short8 as_s8(uint4 u){ short8 r; __builtin_memcpy(&r,&u,16); return r; }

// l-grouped row index: rows[lm] = O_l + n*(2l+1) + m
__device__ __forceinline__ void node_rows(int n, int O0,int O1,int O2,int O3, int* rows){
  rows[0]=O0+n;
  int r1=O1+n*3;
  rows[1]=r1; rows[2]=r1+1; rows[3]=r1+2;
  int r2=O2+n*5;
  #pragma unroll
  for(int m=0;m<5;m++) rows[4+m]=r2+m;
  int r3=O3+n*7;
  #pragma unroll
  for(int m=0;m<7;m++) rows[9+m]=r3+m;
}

// Real sph harmonics l=0..3 (times sqrt(4pi)) of unit vector (x,y,z)
__device__ __forceinline__ void sph16(float x, float y, float z, float* Y){
  float x2=x*x, y2=y*y, z2=z*z;
  Y[0]=SQ4PI*0.28209479177387814f;
  Y[1]=SQ4PI*0.4886025119029199f*y;
  Y[2]=SQ4PI*0.4886025119029199f*z;
  Y[3]=SQ4PI*0.4886025119029199f*x;
  Y[4]=SQ4PI*1.0925484305920792f*x*y;
  Y[5]=SQ4PI*1.0925484305920792f*y*z;
  Y[6]=SQ4PI*0.31539156525252005f*(3.f*z2-1.f);
  Y[7]=SQ4PI*1.0925484305920792f*x*z;
  Y[8]=SQ4PI*0.5462742152960396f*(x2-y2);
  Y[9]=SQ4PI*0.5900435899266435f*y*(3.f*x2-y2);
  Y[10]=SQ4PI*2.890611442640554f*x*y*z;
  Y[11]=SQ4PI*0.4570457994644658f*y*(5.f*z2-1.f);
  Y[12]=SQ4PI*0.3731763325901154f*z*(5.f*z2-3.f);
  Y[13]=SQ4PI*0.4570457994644658f*x*(5.f*z2-1.f);
  Y[14]=SQ4PI*1.445305721320277f*z*(x2-y2);
  Y[15]=SQ4PI*0.5900435899266435f*x*(x2-3.f*y2);
}

// radial basis ef[8] = bess*fcut and d(ef)/dr (table builder only)
__device__ __forceinline__ void radial(float r, float* ef, float* def){
  const float PI_ = 3.14159265358979323846f;
  const float c = 0.6324555320336759f; // sqrt(2/5)
  float xr = r*(1.0f/RMAXF);
  float x2=xr*xr, x3=x2*xr, x5=x3*x2, x6=x5*xr, x7=x6*xr, x8=x7*xr;
  float fcut = 1.f - 28.f*x6 + 48.f*x7 - 21.f*x8;
  float om = 1.f - xr;
  float dfcut = -168.f*x5*om*om*(1.0f/RMAXF);
  float invr = 1.f/r;
  #pragma unroll
  for(int n=1;n<=8;n++){
    float a = (float)n*PI_*(1.0f/RMAXF);
    float ar = a*r;
    float s, co;
    sincosf(ar, &s, &co);
    float b = c*s*invr;
    ef[n-1] = b*fcut;
    def[n-1] = c*(a*co - s*invr)*invr*fcut + b*dfcut;
  }
}

// -------- fused prep: tab | pack | embed | zero-forces | count -----------
__global__ __launch_bounds__(64) void prep_k(
    const float* __restrict__ W_r1, const float* __restrict__ W_r2,
    const float* __restrict__ W_mix,
    const float* __restrict__ attrs, const float* __restrict__ W_embed,
    const float* __restrict__ ae,
    const float* __restrict__ pos, const float* __restrict__ shifts,
    const int* __restrict__ eidx,
    float* __restrict__ w_tab, float* __restrict__ dw_tab,
    unsigned int* __restrict__ Wpc, unsigned int* __restrict__ Wpr,
    float* __restrict__ h, float* __restrict__ node_e,
    float* __restrict__ forces, int* __restrict__ deg,
    int N, int E, int FZ)
{
  __shared__ float s_sil[64], s_ds[64];
  int b = blockIdx.x, lane = threadIdx.x;
  if(b < NPTS){
    float r = fmaxf((float)b * (RMAXF/(float)(NPTS-1)), 1e-6f);
    float ef[8], def[8];
    radial(r, ef, def);
    float t = 0.f, dt = 0.f;
    #pragma unroll
    for(int j=0;j<8;j++){ t += ef[j]*W_r1[j*64+lane]; dt += def[j]*W_r1[j*64+lane]; }
    float sig = 1.f/(1.f+expf(-t));
    s_sil[lane] = t*sig;
    s_ds[lane]  = sig*(1.f + t*(1.f-sig))*dt;
    __syncthreads();
    float w = 0.f, dw = 0.f;
    for(int j=0;j<64;j++){
      w  += s_sil[j]*W_r2[j*64+lane];
      dw += s_ds[j] *W_r2[j*64+lane];
    }
    w_tab[b*64+lane]  = w;
    dw_tab[b*64+lane] = dw;
  } else if(b < NPTS+128){
    int i = (b-NPTS)*64 + lane;   // i < 8192
    int l = i >> 11, a = (i >> 5) & 63, p = i & 31;
    Wpc[i] = pkbf(W_mix[l*4096 + (2*p)*64 + a], W_mix[l*4096 + (2*p+1)*64 + a]);
    Wpr[i] = pkbf(W_mix[l*4096 + a*64 + 2*p], W_mix[l*4096 + a*64 + 2*p+1]);
  } else if(b < NPTS+128+N){
    int n = b - NPTS - 128;
    float acc = 0.f;
    #pragma unroll
    for(int s=0;s<10;s++) acc += attrs[n*10+s]*W_embed[s*64+lane];
    h[(size_t)n*64+lane] = acc;
    if(lane==0){
      float e0 = 0.f;
      #pragma unroll
      for(int s=0;s<10;s++) e0 += attrs[n*10+s]*ae[s];
      node_e[2*n] = e0;
    }
  } else if(b < NPTS+128+N+FZ){
    int i = (b - NPTS - 128 - N)*64 + lane;
    if(i < 3*N) forces[i] = 0.f;
  } else {
    int e = (b - NPTS - 128 - N - FZ)*64 + lane;
    if(e < E){
      int snd = eidx[e], rcv = eidx[E+e];
      float vx = pos[rcv*3+0]-pos[snd*3+0]+shifts[e*3+0];
      float vy = pos[rcv*3+1]-pos[snd*3+1]+shifts[e*3+1];
      float vz = pos[rcv*3+2]-pos[snd*3+2]+shifts[e*3+2];
      float r2 = vx*vx+vy*vy+vz*vz + 1e-12f;
      if(r2 < RMAXF*RMAXF) atomicAdd(&deg[rcv], 1);
    }
  }
}

// ---------------- prefix scan over deg (1 block, 1024 threads) ------------
__global__ __launch_bounds__(1024) void scan_k(
    const int* __restrict__ deg, int* __restrict__ rowptr,
    int* __restrict__ cursor, int N)
{
  __shared__ int part[1024];
  int tid = threadIdx.x;
  int chunk = (N + 1023) / 1024;
  int begin = tid*chunk, end = begin+chunk < N ? begin+chunk : N;
  int s = 0;
  for(int i=begin;i<end;i++) s += deg[i];
  part[tid] = s;
  __syncthreads();
  for(int off=1; off<1024; off<<=1){
    int t = (tid >= off) ? part[tid-off] : 0;
    __syncthreads();
    part[tid] += t;
    __syncthreads();
  }
  int run = part[tid] - s;   // exclusive prefix of this thread's chunk
  for(int i=begin;i<end;i++){
    rowptr[i] = run; cursor[i] = run; run += deg[i];
  }
  if(tid == 1023) rowptr[N] = part[1023];
}

__global__ __launch_bounds__(256) void scatter_k(
    const float* __restrict__ pos, const float* __restrict__ shifts,
    const int* __restrict__ eidx, int* __restrict__ cursor,
    int* __restrict__ elist, int E)
{
  int e = blockIdx.x*256 + threadIdx.x;
  if(e >= E) return;
  int snd = eidx[e], rcv = eidx[E+e];
  float vx = pos[rcv*3+0]-pos[snd*3+0]+shifts[e*3+0];
  float vy = pos[rcv*3+1]-pos[snd*3+1]+shifts[e*3+1];
  float vz = pos[rcv*3+2]-pos[snd*3+2]+shifts[e*3+2];
  float r2 = vx*vx+vy*vy+vz*vz + 1e-12f;
  if(r2 < RMAXF*RMAXF){
    int p = atomicAdd(&cursor[rcv], 1);
    elist[p] = e;
  }
}

// ---------------- edge forward: FOUR waves per node, LDS combine ----------
__device__ __forceinline__ void fwd_body(
    int e, const float* __restrict__ pos, const float* __restrict__ shifts,
    const int* __restrict__ eidx, const float* __restrict__ h,
    const float* __restrict__ w_tab,
    float px, float py, float pz, int lane, float* acc)
{
  int snd = eidx[e];
  float vx = px - pos[snd*3+0] + shifts[e*3+0];
  float vy = py - pos[snd*3+1] + shifts[e*3+1];
  float vz = pz - pos[snd*3+2] + shifts[e*3+2];
  float r = sqrtf(vx*vx+vy*vy+vz*vz + 1e-12f);
  float invr = 1.f/r;
  float Y[16]; sph16(vx*invr, vy*invr, vz*invr, Y);
  float rs = r*TAB_SCALE;
  int i0 = (int)rs; i0 = i0 < NPTS-2 ? i0 : NPTS-2;
  float fr = rs - (float)i0;
  const float* t0 = w_tab + i0*64 + lane;
  float w0 = t0[0], w1 = t0[64];
  float w = w0 + fr*(w1-w0);
  float wh = w * h[(size_t)snd*64+lane] * INV_AVG;
  #pragma unroll
  for(int lm=0;lm<16;lm++) acc[lm] += wh*Y[lm];
}

__global__ __launch_bounds__(256) void fwd_tab(
    const float* __restrict__ pos, const float* __restrict__ shifts,
    const int* __restrict__ eidx, const float* __restrict__ h,
    const float* __restrict__ w_tab,
    const int* __restrict__ rowptr, const int* __restrict__ elist,
    unsigned int* __restrict__ AhL, int N, int E,
    int O0,int O1,int O2,int O3)
{
  __shared__ float sBuf[3][16][64];
  int tid = threadIdx.x, wv = tid >> 6, lane = tid & 63;
  int n = blockIdx.x;
  if(n >= N) return;
  float acc[16];
  #pragma unroll
  for(int lm=0;lm<16;lm++) acc[lm] = 0.f;
  int beg = rowptr[n], endp = rowptr[n+1];
  float px = pos[n*3+0], py = pos[n*3+1], pz = pos[n*3+2];
  for(int idx = beg + wv; idx < endp; idx += 4)
    fwd_body(elist[idx], pos, shifts, eidx, h, w_tab, px,py,pz, lane, acc);
  if(wv){
    #pragma unroll
    for(int lm=0;lm<16;lm++) sBuf[wv-1][lm][lane] = acc[lm];
  }
  __syncthreads();
  if(wv == 0){
    int rows[16]; node_rows(n,O0,O1,O2,O3,rows);
    #pragma unroll
    for(int lm=0;lm<16;lm++){
      float v = acc[lm] + sBuf[0][lm][lane] + sBuf[1][lm][lane] + sBuf[2][lm][lane];
      float nb = __shfl_xor(v, 1, 64);
      if(!(lane&1)) AhL[(size_t)rows[lm]*32 + (lane>>1)] = pkbf(v, nb);
    }
  }
}

// ---------------- node GEMM (+ optional fused energy reduction) -----------
__global__ __launch_bounds__(256) void gemm_k(
    const unsigned int* __restrict__ Asrc,
    const unsigned int* __restrict__ Wsrc,
    unsigned int* __restrict__ Cdst,
    int t1, int t2, int t3, int T, int G1,
    const float* __restrict__ node_e, const int* __restrict__ batch,
    float* __restrict__ e_acc, int N, int G)
{
  if((int)blockIdx.x >= G1){
    // fused ered: blocks [G1, gridDim)
    __shared__ float sE[64];
    int tid = threadIdx.x;
    int bid = blockIdx.x - G1, nb = gridDim.x - G1;
    if(tid < 2*G) sE[tid] = 0.f;
    __syncthreads();
    for(int i = bid*256 + tid; i < N; i += nb*256){
      int g = batch[i];
      atomicAdd(&sE[2*g],   node_e[2*i]);
      atomicAdd(&sE[2*g+1], node_e[2*i+1]);
    }
    __syncthreads();
    if(tid < 2*G) atomicAdd(&e_acc[tid], sE[tid]);
    return;
  }
  int wv = threadIdx.x >> 6, lane = threadIdx.x & 63;
  int lrow = lane & 15, lblk = lane >> 4;
  for(int t = blockIdx.x*4 + wv; t < T; t += G1*4){
    int l = (t < t1) ? 0 : ((t < t2) ? 1 : ((t < t3) ? 2 : 3));
    const unsigned int* Wb = Wsrc + l*2048;
    int rowbase = t*16;
    const uint4* arow = (const uint4*)(Asrc + (size_t)rowbase*32);
    short8 aF0 = as_s8(arow[lrow*8 + lblk]);
    short8 aF1 = as_s8(arow[lrow*8 + 4 + lblk]);
    #pragma unroll
    for(int j=0;j<4;j++){
      int c = j*16 + lrow;
      uint4 b0u = *(const uint4*)(Wb + c*32 + lblk*4);
      uint4 b1u = *(const uint4*)(Wb + c*32 + 16 + lblk*4);
      f32x4 acc = {0.f,0.f,0.f,0.f};
      acc = __builtin_amdgcn_mfma_f32_16x16x32_bf16(aF0, as_s8(b0u), acc, 0,0,0);
      acc = __builtin_amdgcn_mfma_f32_16x16x32_bf16(aF1, as_s8(b1u), acc, 0,0,0);
      #pragma unroll
      for(int r=0;r<4;r++){
        float v = acc[r];
        float nb = __shfl_xor(v, 1, 64);
        if(!(lane&1)){
          int grow = rowbase + lblk*4 + r;
          Cdst[(size_t)grow*32 + j*8 + (lrow>>1)] = pkbf(v, nb);
        }
      }
    }
  }
}

// ---------------- node nonlinear middle: s, B, e1, gAm --------------------
__global__ __launch_bounds__(256) void mid_k(
    const unsigned int* __restrict__ AmH,
    const float* __restrict__ W_prod, const float* __restrict__ w_ro,
    float* __restrict__ node_e,
    unsigned int* __restrict__ gAmL, int N, int O0,int O1,int O2,int O3)
{
  int wv = threadIdx.x >> 6, lane = threadIdx.x & 63;
  int n = blockIdx.x*4 + wv;
  if(n >= N) return;
  int rows[16]; node_rows(n,O0,O1,O2,O3,rows);
  float am[16];
  #pragma unroll
  for(int lm=0;lm<16;lm++){
    unsigned int u = AmH[(size_t)rows[lm]*32 + (lane>>1)];
    am[lm] = (lane&1) ? unhi(u) : unlo(u);
  }
  float s_ = 0.f;
  #pragma unroll
  for(int lm=0;lm<16;lm++) s_ += am[lm]*am[lm];
  float a0_ = am[0];
  float wp0 = W_prod[lane], wp1 = W_prod[64+lane], wp2 = W_prod[128+lane];
  float wr = w_ro[lane];
  float Bv = wp0*a0_ + wp1*s_ + wp2*a0_*s_;
  float v = Bv*wr;
  #pragma unroll
  for(int off=32; off; off>>=1) v += __shfl_xor(v, off, 64);
  if(lane==0) node_e[2*n+1] = v;
  float gs = wr*(wp1 + wp2*a0_);
  #pragma unroll
  for(int lm=0;lm<16;lm++){
    float g = gs*2.f*am[lm];
    if(lm==0) g += wr*(wp0 + wp2*s_);
    float nb = __shfl_xor(g, 1, 64);
    if(!(lane&1)) gAmL[(size_t)rows[lm]*32 + (lane>>1)] = pkbf(g, nb);
  }
}

// ---------------- edge backward: one wave per edge (+ fused fin) ----------
__global__ __launch_bounds__(256) void bwd_edge(
    const float* __restrict__ pos, const float* __restrict__ shifts,
    const int* __restrict__ eidx, const float* __restrict__ h,
    const float* __restrict__ w_tab, const float* __restrict__ dw_tab,
    const unsigned int* __restrict__ gAH,
    const int* __restrict__ nselp, const int* __restrict__ elist,
    float* __restrict__ forces, int E,
    int O0,int O1,int O2,int O3,
    const float* __restrict__ e_acc, float* __restrict__ out, int G)
{
  int tid = threadIdx.x, wv = tid >> 6, lane = tid & 63;
  if(blockIdx.x == gridDim.x-1){
    // fused finalize (e_acc complete from previous launch)
    if(tid < G){
      float e0 = e_acc[2*tid], e1 = e_acc[2*tid+1];
      out[tid] = e0+e1;
      out[G + 2*tid] = e0;
      out[G + 2*tid+1] = e1;
    }
    return;
  }
  int widx = blockIdx.x*4 + wv;
  if(widx >= *nselp) return;
  int e = elist[widx];
  int snd = eidx[e], rcv = eidx[E+e];
  int rows[16]; node_rows(rcv,O0,O1,O2,O3,rows);
  float gm[16];
  #pragma unroll
  for(int lm=0;lm<16;lm++){
    unsigned int u = gAH[(size_t)rows[lm]*32 + (lane>>1)];
    gm[lm] = ((lane&1) ? unhi(u) : unlo(u)) * INV_AVG;
  }
  float vx = pos[rcv*3+0] - pos[snd*3+0] + shifts[e*3+0];
  float vy = pos[rcv*3+1] - pos[snd*3+1] + shifts[e*3+1];
  float vz = pos[rcv*3+2] - pos[snd*3+2] + shifts[e*3+2];
  float r = sqrtf(vx*vx+vy*vy+vz*vz + 1e-12f);
  float invr = 1.f/r;
  float x=vx*invr, y=vy*invr, z=vz*invr;
  float Y[16]; sph16(x,y,z,Y);
  float rs = r*TAB_SCALE;
  int i0 = (int)rs; i0 = i0 < NPTS-2 ? i0 : NPTS-2;
  float fr = rs - (float)i0;
  const float* t0 = w_tab  + i0*64 + lane;
  const float* d0 = dw_tab + i0*64 + lane;
  float w    = t0[0] + fr*(t0[64]-t0[0]);
  float dwdr = d0[0] + fr*(d0[64]-d0[0]);
  float hk = h[(size_t)snd*64+lane];
  float wh = w*hk;
  float gw = 0.f;
  #pragma unroll
  for(int lm=0;lm<16;lm++) gw += gm[lm]*Y[lm];
  gw *= hk;
  const float c1=0.4886025119029199f, c2=1.0925484305920792f, c3=0.31539156525252005f;
  const float c4=0.5462742152960396f, c5=0.5900435899266435f, c6=2.890611442640554f;
  const float c7=0.4570457994644658f, c8=0.3731763325901154f, c9=1.445305721320277f;
  float x2=x*x, y2=y*y, z2=z*z;
  float fz1 = 5.f*z2-1.f;
  float gxp = c1*gm[3] + c2*(y*gm[4] + z*gm[7]) + 2.f*c4*x*gm[8]
            + 6.f*c5*x*y*gm[9] + c6*y*z*gm[10] + c7*fz1*gm[13]
            + 2.f*c9*x*z*gm[14] + 3.f*c5*(x2-y2)*gm[15];
  float gyp = c1*gm[1] + c2*(x*gm[4] + z*gm[5]) - 2.f*c4*y*gm[8]
            + 3.f*c5*(x2-y2)*gm[9] + c6*x*z*gm[10] + c7*fz1*gm[11]
            - 2.f*c9*y*z*gm[14] - 6.f*c5*x*y*gm[15];
  float gzp = c1*gm[2] + c2*(y*gm[5] + x*gm[7]) + 6.f*c3*z*gm[6]
            + c6*x*y*gm[10] + 10.f*c7*y*z*gm[11] + c8*(15.f*z2-3.f)*gm[12]
            + 10.f*c7*x*z*gm[13] + c9*(x2-y2)*gm[14];
  float gx = gxp*wh*SQ4PI, gy = gyp*wh*SQ4PI, gz = gzp*wh*SQ4PI;
  float grp = gw*dwdr;
  #pragma unroll
  for(int off=32; off; off>>=1){
    gx  += __shfl_xor(gx,  off, 64);
    gy  += __shfl_xor(gy,  off, 64);
    gz  += __shfl_xor(gz,  off, 64);
    grp += __shfl_xor(grp, off, 64);
  }
  float udot = x*gx + y*gy + z*gz;
  float gvx = grp*x + (gx - udot*x)*invr;
  float gvy = grp*y + (gy - udot*y)*invr;
  float gvz = grp*z + (gz - udot*z)*invr;
  if(lane==0){
    atomicAdd(&forces[snd*3+0],  gvx);
    atomicAdd(&forces[snd*3+1],  gvy);
    atomicAdd(&forces[snd*3+2],  gvz);
    atomicAdd(&forces[rcv*3+0], -gvx);
    atomicAdd(&forces[rcv*3+1], -gvy);
    atomicAdd(&forces[rcv*3+2], -gvz);
  }
}

extern "C" void kernel_launch(void* const* d_in, const int* in_sizes, int n_in,
                              void* d_out, int out_size, void* d_ws, size_t ws_size,
                              hipStream_t stream) {
  const float* positions  = (const float*)d_in[0];
  const float* node_attrs = (const float*)d_in[1];
  const float* shifts     = (const float*)d_in[2];
  const float* W_embed    = (const float*)d_in[3];
  const float* at_en      = (const float*)d_in[4];
  const float* W_r1       = (const float*)d_in[5];
  const float* W_r2       = (const float*)d_in[6];
  const float* W_mix      = (const float*)d_in[7];
  const float* W_prod     = (const float*)d_in[8];
  const float* w_ro       = (const float*)d_in[9];
  const int*   edge_index = (const int*)d_in[10];
  const int*   batch      = (const int*)d_in[11];

  int N = in_sizes[0]/3;
  int E = in_sizes[10]/2;
  int G = (out_size - 3*N)/3;

  // l-grouped rows, each region padded to multiple of 16
  int Mp0 = (N   + 15) & ~15;
  int Mp1 = (3*N + 15) & ~15;
  int Mp2 = (5*N + 15) & ~15;
  int Mp3 = (7*N + 15) & ~15;
  int O0 = 0, O1 = Mp0, O2 = O1 + Mp1, O3 = O2 + Mp2;
  int Mp = O3 + Mp3;
  int T   = Mp  / 16;
  int tt1 = Mp0 / 16;
  int tt2 = tt1 + Mp1/16;
  int tt3 = tt2 + Mp2/16;
  int G1  = (T+3)/4;

  float* out = (float*)d_out;
  unsigned int* AhL  = (unsigned int*)d_ws;       // [Mp][32] bf16 pairs; reused as gAH
  unsigned int* AmH  = AhL + (size_t)Mp*32;       // [Mp][32]
  unsigned int* gAmL = AmH + (size_t)Mp*32;       // [Mp][32]
  float* h      = (float*)(gAmL + (size_t)Mp*32); // N*64
  float* w_tab  = h + (size_t)N*64;               // NPTS*64
  float* dw_tab = w_tab + (size_t)NPTS*64;        // NPTS*64
  unsigned int* Wpc = (unsigned int*)(dw_tab + (size_t)NPTS*64); // 8192
  unsigned int* Wpr = Wpc + 8192;                 // 8192
  float* eacc   = (float*)(Wpr + 8192);           // 2G   (zeroed)
  int*   deg    = (int*)(eacc + 2*G);             // N    (zeroed, contiguous w/ eacc)
  float* node_e = (float*)(deg + N);              // 2N
  int*   rowptr = (int*)(node_e + 2*N);           // N+1  (rowptr[N] = nsel)
  int*   cursor = rowptr + N + 1;                 // N
  int*   elist  = cursor + N;                     // E

  int FZ = (3*N + 63)/64;
  int CB = (E + 63)/64;

  hipMemsetAsync(eacc, 0, (size_t)(2*G + N)*sizeof(int), stream);  // eacc + deg

  prep_k<<<NPTS + 128 + N + FZ + CB, 64, 0, stream>>>(
      W_r1, W_r2, W_mix, node_attrs, W_embed, at_en,
      positions, shifts, edge_index,
      w_tab, dw_tab, Wpc, Wpr, h, node_e, out + 3*G, deg, N, E, FZ);
  scan_k<<<1, 1024, 0, stream>>>(deg, rowptr, cursor, N);
  scatter_k<<<(E+255)/256, 256, 0, stream>>>(positions, shifts, edge_index, cursor, elist, E);
  fwd_tab<<<N, 256, 0, stream>>>(positions, shifts, edge_index, h, w_tab,
                                 rowptr, elist, AhL, N, E, O0,O1,O2,O3);
  gemm_k<<<G1, 256, 0, stream>>>(AhL, Wpc, AmH, tt1, tt2, tt3, T, G1,
                                 nullptr, nullptr, nullptr, 0, 0);
  mid_k<<<(N+3)/4, 256, 0, stream>>>(AmH, W_prod, w_ro, node_e, gAmL, N, O0,O1,O2,O3);
  gemm_k<<<G1 + 16, 256, 0, stream>>>(gAmL, Wpr, AhL, tt1, tt2, tt3, T, G1,
                                      node_e, batch, eacc, N, G);
  bwd_edge<<<(E+3)/4 + 1, 256, 0, stream>>>(positions, shifts, edge_index, h, w_tab, dw_tab,
                                            AhL, rowptr + N, elist, out + 3*G, E,
                                            O0,O1,O2,O3, eacc, out, G);
}